// Round 1
// baseline (9431.264 us; speedup 1.0000x reference)
//
#include <hip/hip_runtime.h>
#include <hip/hip_cooperative_groups.h>
#include <math.h>

namespace cg = cooperative_groups;

#define NN 60000
#define BB 8
#define FF 384
#define EE 600000
#define HH 6
#define CC 10
#define HT_BITS 20
#define HT_SIZE (1u << HT_BITS)
#define HT_MASK (HT_SIZE - 1u)
#define TPB 256

static inline int ngrid(int n) { return (n + TPB - 1) / TPB; }

// ---------- helpers ----------
__device__ __forceinline__ unsigned int encf(float v) {
  unsigned int b = __float_as_uint(v);
  return (b & 0x80000000u) ? ~b : (b | 0x80000000u);
}
__device__ __forceinline__ float decf(unsigned int u) {
  unsigned int b = (u & 0x80000000u) ? (u & 0x7FFFFFFFu) : ~u;
  return __uint_as_float(b);
}
__device__ __forceinline__ unsigned long long prio(const float* score, int e) {
  return (((unsigned long long)__float_as_uint(score[e])) << 32) |
         (unsigned int)(~(unsigned int)e);
}

// ---------- stage 1 matmul: h1pre = x @ W1 (N x 384 @ 384 x 6) ----------
__global__ void k_mm1(const float* __restrict__ x, const float* __restrict__ W,
                      float* __restrict__ out) {
  __shared__ float Ws[FF * HH];
  for (int i = threadIdx.x; i < FF * HH; i += blockDim.x) Ws[i] = W[i];
  __syncthreads();
  int wave = threadIdx.x >> 6, lane = threadIdx.x & 63;
  int node = blockIdx.x * 4 + wave;
  if (node >= NN) return;
  const float* xr = x + (size_t)node * FF;
  float acc[HH] = {0.f, 0.f, 0.f, 0.f, 0.f, 0.f};
  for (int k = lane; k < FF; k += 64) {
    float xv = xr[k];
#pragma unroll
    for (int j = 0; j < HH; j++) acc[j] += xv * Ws[k * HH + j];
  }
#pragma unroll
  for (int j = 0; j < HH; j++) {
#pragma unroll
    for (int o = 32; o > 0; o >>= 1) acc[j] += __shfl_down(acc[j], o, 64);
  }
  if (lane == 0) {
#pragma unroll
    for (int j = 0; j < HH; j++) out[(size_t)node * HH + j] = acc[j];
  }
}

// ---------- stage 2 matmul: h2pre = newx1 @ W2 (N x 6 @ 6 x 10) ----------
__global__ void k_mm2(const float* __restrict__ x, const float* __restrict__ W,
                      float* __restrict__ out) {
  int v = blockIdx.x * blockDim.x + threadIdx.x;
  if (v >= NN) return;
  float xv[HH];
#pragma unroll
  for (int j = 0; j < HH; j++) xv[j] = x[(size_t)v * HH + j];
#pragma unroll
  for (int c = 0; c < CC; c++) {
    float a = 0.f;
#pragma unroll
    for (int j = 0; j < HH; j++) a += xv[j] * W[j * CC + c];
    out[(size_t)v * CC + c] = a;
  }
}

// ---------- generic GCN conv pieces ----------
__global__ void k_deg(const int* __restrict__ src, const int* __restrict__ dst,
                      const unsigned char* __restrict__ ev, float* __restrict__ deg,
                      unsigned char* __restrict__ hasloop) {
  int e = blockIdx.x * blockDim.x + threadIdx.x;
  if (e >= EE) return;
  if (ev && !ev[e]) return;
  int d = dst[e];
  atomicAdd(&deg[d], 1.0f);
  if (src[e] == d) hasloop[d] = 1;
}

__global__ void k_dinv(const float* __restrict__ deg, const unsigned char* __restrict__ hasloop,
                       const unsigned char* __restrict__ nv, float* __restrict__ dinv,
                       unsigned char* __restrict__ addloop) {
  int v = blockIdx.x * blockDim.x + threadIdx.x;
  if (v >= NN) return;
  int nvv = nv ? (int)nv[v] : 1;
  unsigned char al = (nvv && !hasloop[v]) ? 1 : 0;
  float d = deg[v] + (float)al;
  dinv[v] = d > 0.f ? 1.0f / sqrtf(fmaxf(d, 1e-12f)) : 0.f;
  addloop[v] = al;
}

__global__ void k_gcn_agg(const int* __restrict__ src, const int* __restrict__ dst,
                          const unsigned char* __restrict__ ev, const float* __restrict__ dinv,
                          const float* __restrict__ h, float* __restrict__ out, int fd) {
  int e = blockIdx.x * blockDim.x + threadIdx.x;
  if (e >= EE) return;
  if (ev && !ev[e]) return;
  int s = src[e], d = dst[e];
  float c = dinv[s] * dinv[d];
  for (int j = 0; j < fd; j++)
    atomicAdd(&out[(size_t)d * fd + j], h[(size_t)s * fd + j] * c);
}

__global__ void k_gcn_fin(const float* __restrict__ h, const float* __restrict__ dinv,
                          const unsigned char* __restrict__ addloop, const float* __restrict__ b,
                          float* __restrict__ out, int fd, int relu) {
  int v = blockIdx.x * blockDim.x + threadIdx.x;
  if (v >= NN) return;
  float c = addloop[v] ? dinv[v] * dinv[v] : 0.f;
  for (int j = 0; j < fd; j++) {
    float o = out[(size_t)v * fd + j] + c * h[(size_t)v * fd + j] + b[j];
    if (relu) o = fmaxf(o, 0.f);
    out[(size_t)v * fd + j] = o;
  }
}

// ---------- edge pool: scores ----------
__global__ void k_raw(const float* __restrict__ x, const int* __restrict__ src,
                      const int* __restrict__ dst, const unsigned char* __restrict__ ev,
                      const float* __restrict__ Wp, const float* __restrict__ bp,
                      float* __restrict__ raw, unsigned int* __restrict__ mEnc, int fd) {
  int e = blockIdx.x * blockDim.x + threadIdx.x;
  if (e >= EE) return;
  if (ev && !ev[e]) return;
  int s = src[e], d = dst[e];
  float r = bp[0];
  for (int j = 0; j < fd; j++) r += x[(size_t)s * fd + j] * Wp[j];
  for (int j = 0; j < fd; j++) r += x[(size_t)d * fd + j] * Wp[fd + j];
  raw[e] = r;
  atomicMax(&mEnc[d], encf(r));
}

__global__ void k_exps(const float* __restrict__ raw, const int* __restrict__ dst,
                       const unsigned char* __restrict__ ev, const unsigned int* __restrict__ mEnc,
                       float* __restrict__ ex, float* __restrict__ ssum) {
  int e = blockIdx.x * blockDim.x + threadIdx.x;
  if (e >= EE) return;
  if (ev && !ev[e]) return;
  int d = dst[e];
  unsigned int me = mEnc[d];
  float m = me ? decf(me) : 0.f;
  float v = expf(raw[e] - m);
  ex[e] = v;
  atomicAdd(&ssum[d], v);
}

__global__ void k_score(const float* __restrict__ ex, const int* __restrict__ dst,
                        const unsigned char* __restrict__ ev, const float* __restrict__ ssum,
                        float* __restrict__ score) {
  int e = blockIdx.x * blockDim.x + threadIdx.x;
  if (e >= EE) return;
  if (ev && !ev[e]) return;
  float sd = ssum[dst[e]];
  score[e] = ex[e] / (sd > 0.f ? sd : 1.0f) + 0.5f;
}

// ---------- matching: locally-dominant greedy (== sequential greedy) ----------
// cooperative kernel, compacted live-edge lists
__global__ void k_match(const int* __restrict__ src, const int* __restrict__ dst,
                        const float* __restrict__ score, const unsigned char* __restrict__ evalid,
                        unsigned char* __restrict__ rem, unsigned char* __restrict__ chosen,
                        unsigned long long* __restrict__ best, int* __restrict__ elist0,
                        int* __restrict__ elist1, int* __restrict__ cnts) {
  cg::grid_group g = cg::this_grid();
  int nt = gridDim.x * blockDim.x;
  int tid = blockIdx.x * blockDim.x + threadIdx.x;
  int lane = threadIdx.x & 63;

  if (tid == 0) { cnts[0] = 0; cnts[1] = 0; }
  g.sync();
  // build initial list of valid edges (wave-aggregated append)
  for (int e = tid; e < EE; e += nt) {
    int ok = evalid ? (evalid[e] ? 1 : 0) : 1;
    unsigned long long m = __ballot(ok);
    int tot = __popcll(m);
    int pre = __popcll(m & ((1ULL << lane) - 1ULL));
    int base = 0;
    if (lane == 0 && tot) base = atomicAdd(&cnts[0], tot);
    base = __shfl(base, 0, 64);
    if (ok) elist0[base + pre] = e;
  }
  __threadfence();
  g.sync();

  int cur = 0;
  int* lists[2] = {elist0, elist1};
  for (int round = 0; round < 100000; round++) {
    int n = *(volatile int*)&cnts[cur];
    if (n == 0) break;
    if (tid == 0) cnts[cur ^ 1] = 0;
    // A: clear best at live endpoints
    for (int i = tid; i < n; i += nt) {
      int e = lists[cur][i];
      best[src[e]] = 0ULL;
      best[dst[e]] = 0ULL;
    }
    __threadfence();
    g.sync();
    // B: post priorities
    for (int i = tid; i < n; i += nt) {
      int e = lists[cur][i];
      int s = src[e], d = dst[e];
      if (!rem[s] || !rem[d]) continue;
      unsigned long long p = prio(score, e);
      atomicMax(&best[s], p);
      if (d != s) atomicMax(&best[d], p);
    }
    __threadfence();
    g.sync();
    // C: select local winners, compact survivors
    for (int i = tid; i < n; i += nt) {
      int e = lists[cur][i];
      int s = src[e], d = dst[e];
      int keep = 0;
      if (rem[s] && rem[d]) {
        unsigned long long p = prio(score, e);
        if (best[s] == p && best[d] == p) {
          chosen[e] = 1;
          rem[s] = 0;
          rem[d] = 0;
        } else {
          keep = 1;
        }
      }
      unsigned long long m = __ballot(keep);
      int tot = __popcll(m);
      int pre = __popcll(m & ((1ULL << lane) - 1ULL));
      int base = 0;
      if (lane == 0 && tot) base = atomicAdd(&cnts[cur ^ 1], tot);
      base = __shfl(base, 0, 64);
      if (keep) lists[cur ^ 1][base + pre] = e;
    }
    __threadfence();
    g.sync();
    cur ^= 1;
  }
}

// ---------- edge pool: post-matching ----------
__global__ void k_pool_node(const unsigned char* __restrict__ nvin, unsigned char* __restrict__ nvout,
                            float* __restrict__ scale) {
  int v = blockIdx.x * blockDim.x + threadIdx.x;
  if (v >= NN) return;
  nvout[v] = nvin ? nvin[v] : 1;
  scale[v] = 1.0f;
}

__global__ void k_pool_edge(const int* __restrict__ src, const int* __restrict__ dst,
                            const unsigned char* __restrict__ chosen, const float* __restrict__ score,
                            const float* __restrict__ x, unsigned char* __restrict__ nvout,
                            float* __restrict__ scale, float* __restrict__ added,
                            int* __restrict__ merged, int fd) {
  int e = blockIdx.x * blockDim.x + threadIdx.x;
  if (e >= EE) return;
  if (!chosen[e]) return;
  int s = src[e], d = dst[e];
  scale[s] = score[e];
  if (merged) merged[d] = s;
  if (s != d) {
    nvout[d] = 0;
    for (int j = 0; j < fd; j++) added[(size_t)s * fd + j] = x[(size_t)d * fd + j];
  }
}

__global__ void k_newx(const float* __restrict__ x, const float* __restrict__ added,
                       const float* __restrict__ scale, const unsigned char* __restrict__ nvout,
                       float* __restrict__ newx, int fd) {
  int v = blockIdx.x * blockDim.x + threadIdx.x;
  if (v >= NN) return;
  float sc = scale[v];
  int ok = nvout[v];
  for (int j = 0; j < fd; j++)
    newx[(size_t)v * fd + j] =
        ok ? (x[(size_t)v * fd + j] + added[(size_t)v * fd + j]) * sc : 0.f;
}

__global__ void k_cmap(const int* __restrict__ merged, int* __restrict__ cmap) {
  int v = blockIdx.x * blockDim.x + threadIdx.x;
  if (v >= NN) return;
  int m = merged[v];
  cmap[v] = m >= 0 ? m : v;
}

__global__ void k_remap(const int* __restrict__ src, const int* __restrict__ dst,
                        const int* __restrict__ cmap, int* __restrict__ ns, int* __restrict__ nd) {
  int e = blockIdx.x * blockDim.x + threadIdx.x;
  if (e >= EE) return;
  ns[e] = cmap[src[e]];
  nd[e] = cmap[dst[e]];
}

// ---------- dedup via hash: keep min original index per (ns,nd) ----------
__device__ __forceinline__ unsigned int ht_hash(unsigned long long key) {
  return (unsigned int)((key * 0x9E3779B97F4A7C15ULL) >> 44) & HT_MASK;
}

__global__ void k_dedup_ins(const int* __restrict__ ns, const int* __restrict__ nd,
                            unsigned long long* __restrict__ htab) {
  int e = blockIdx.x * blockDim.x + threadIdx.x;
  if (e >= EE) return;
  unsigned long long key =
      (unsigned long long)((((unsigned int)ns[e]) << 16) | (unsigned int)nd[e]);
  unsigned long long val = (key << 32) | (unsigned int)e;
  unsigned int h = ht_hash(key);
  for (;;) {
    unsigned long long curv = htab[h];
    if (curv == ~0ULL) {
      unsigned long long prev = atomicCAS(&htab[h], ~0ULL, val);
      if (prev == ~0ULL) break;
      curv = prev;
    }
    if ((curv >> 32) == key) {
      atomicMin(&htab[h], val);
      break;
    }
    h = (h + 1) & HT_MASK;
  }
}

__global__ void k_dedup_mark(const int* __restrict__ ns, const int* __restrict__ nd,
                             const unsigned long long* __restrict__ htab,
                             unsigned char* __restrict__ evout) {
  int e = blockIdx.x * blockDim.x + threadIdx.x;
  if (e >= EE) return;
  unsigned long long key =
      (unsigned long long)((((unsigned int)ns[e]) << 16) | (unsigned int)nd[e]);
  unsigned int h = ht_hash(key);
  for (;;) {
    unsigned long long curv = htab[h];
    if ((curv >> 32) == key) {
      evout[e] = ((curv & 0xFFFFFFFFULL) == (unsigned long long)(unsigned int)e) ? 1 : 0;
      return;
    }
    h = (h + 1) & HT_MASK;
  }
}

// ---------- misc ----------
__global__ void k_copy_u8(const unsigned char* __restrict__ a, unsigned char* __restrict__ b, int n) {
  int i = blockIdx.x * blockDim.x + threadIdx.x;
  if (i < n) b[i] = a[i];
}

__global__ void k_graphpool(const float* __restrict__ h, const unsigned char* __restrict__ nv,
                            const int* __restrict__ batch, float* __restrict__ gsum,
                            float* __restrict__ gcnt) {
  int v = blockIdx.x * blockDim.x + threadIdx.x;
  int lane = threadIdx.x & 63;
  int vc = v < NN ? v : NN - 1;
  int b = batch[vc];
  int active = (v < NN) && nv[v];
  float cnt = active ? 1.f : 0.f;
  float val[CC];
  for (int j = 0; j < CC; j++) val[j] = active ? h[(size_t)v * CC + j] : 0.f;
  int b0 = __shfl(b, 0, 64);
  unsigned long long same = __ballot(b == b0);
  if (same == ~0ULL) {
    for (int o = 32; o > 0; o >>= 1) {
      cnt += __shfl_down(cnt, o, 64);
      for (int j = 0; j < CC; j++) val[j] += __shfl_down(val[j], o, 64);
    }
    if (lane == 0 && cnt > 0.f) {
      atomicAdd(&gcnt[b0], cnt);
      for (int j = 0; j < CC; j++) atomicAdd(&gsum[b0 * CC + j], val[j]);
    }
  } else if (active) {
    atomicAdd(&gcnt[b], cnt);
    for (int j = 0; j < CC; j++) atomicAdd(&gsum[b * CC + j], val[j]);
  }
}

__global__ void k_logsm(const float* __restrict__ gsum, const float* __restrict__ gcnt,
                        float* __restrict__ out) {
  int t = threadIdx.x;
  if (t >= BB) return;
  float gr[CC];
  float c = gcnt[t];
  float m = -INFINITY;
  for (int j = 0; j < CC; j++) {
    gr[j] = gsum[t * CC + j] / c;
    m = fmaxf(m, gr[j]);
  }
  float s = 0.f;
  for (int j = 0; j < CC; j++) s += expf(gr[j] - m);
  float l = logf(s);
  for (int j = 0; j < CC; j++) out[t * CC + j] = gr[j] - m - l;
}

// ---------- host ----------
extern "C" void kernel_launch(void* const* d_in, const int* in_sizes, int n_in,
                              void* d_out, int out_size, void* d_ws, size_t ws_size,
                              hipStream_t stream) {
  const float* x = (const float*)d_in[0];
  const int* src = (const int*)d_in[1];
  const int* dst = (const int*)d_in[2];
  const int* batch = (const int*)d_in[3];
  const float* W1 = (const float*)d_in[4];
  const float* b1 = (const float*)d_in[5];
  const float* W2 = (const float*)d_in[6];
  const float* b2 = (const float*)d_in[7];
  const float* Wp1 = (const float*)d_in[8];
  const float* bp1 = (const float*)d_in[9];
  const float* Wp2 = (const float*)d_in[10];
  const float* bp2 = (const float*)d_in[11];
  float* out = (float*)d_out;

  char* wsb = (char*)d_ws;
  size_t off = 0;
  auto A = [&](size_t bytes) -> char* {
    char* r = wsb + off;
    off = (off + bytes + 255) & ~(size_t)255;
    return r;
  };
  float* h1pre = (float*)A((size_t)NN * HH * 4);
  float* h1out = (float*)A((size_t)NN * HH * 4);
  float* deg = (float*)A((size_t)NN * 4);
  float* dinv = (float*)A((size_t)NN * 4);
  unsigned char* hasloop = (unsigned char*)A(NN);
  unsigned char* addloop = (unsigned char*)A(NN);
  float* raw = (float*)A((size_t)EE * 4);
  float* ex = (float*)A((size_t)EE * 4);
  float* score = (float*)A((size_t)EE * 4);
  unsigned int* mEnc = (unsigned int*)A((size_t)NN * 4);
  float* ssum = (float*)A((size_t)NN * 4);
  unsigned long long* best = (unsigned long long*)A((size_t)NN * 8);
  unsigned char* rem = (unsigned char*)A(NN);
  unsigned char* chosen = (unsigned char*)A(EE);
  unsigned char* nv1 = (unsigned char*)A(NN);
  unsigned char* nv2 = (unsigned char*)A(NN);
  float* scale = (float*)A((size_t)NN * 4);
  float* added = (float*)A((size_t)NN * CC * 4);
  float* newx1 = (float*)A((size_t)NN * HH * 4);
  int* merged = (int*)A((size_t)NN * 4);
  int* cmap = (int*)A((size_t)NN * 4);
  int* ns = (int*)A((size_t)EE * 4);
  int* nd = (int*)A((size_t)EE * 4);
  unsigned char* ev1 = (unsigned char*)A(EE);
  unsigned long long* htab = (unsigned long long*)A((size_t)HT_SIZE * 8);
  float* h2pre = (float*)A((size_t)NN * CC * 4);
  float* h2out = (float*)A((size_t)NN * CC * 4);
  float* newx2 = (float*)A((size_t)NN * CC * 4);
  int* elist0 = (int*)A((size_t)EE * 4);
  int* elist1 = (int*)A((size_t)EE * 4);
  int* cnts = (int*)A(64);
  float* gsum = (float*)A((size_t)BB * CC * 4);
  float* gcnt = (float*)A((size_t)BB * 4);
  (void)ws_size; (void)n_in; (void)in_sizes; (void)out_size;

  const int GE = ngrid(EE), GN = ngrid(NN);

  // ===== stage 1: GCNConv(384->6) + ReLU =====
  hipLaunchKernelGGL(k_mm1, dim3((NN + 3) / 4), dim3(TPB), 0, stream, x, W1, h1pre);
  hipMemsetAsync(deg, 0, (size_t)NN * 4, stream);
  hipMemsetAsync(hasloop, 0, NN, stream);
  hipMemsetAsync(h1out, 0, (size_t)NN * HH * 4, stream);
  hipLaunchKernelGGL(k_deg, dim3(GE), dim3(TPB), 0, stream, src, dst, (const unsigned char*)nullptr, deg, hasloop);
  hipLaunchKernelGGL(k_dinv, dim3(GN), dim3(TPB), 0, stream, deg, hasloop, (const unsigned char*)nullptr, dinv, addloop);
  hipLaunchKernelGGL(k_gcn_agg, dim3(GE), dim3(TPB), 0, stream, src, dst, (const unsigned char*)nullptr, dinv, h1pre, h1out, HH);
  hipLaunchKernelGGL(k_gcn_fin, dim3(GN), dim3(TPB), 0, stream, h1pre, dinv, addloop, b1, h1out, HH, 1);

  // ===== edge pool 1 =====
  hipMemsetAsync(mEnc, 0, (size_t)NN * 4, stream);
  hipMemsetAsync(ssum, 0, (size_t)NN * 4, stream);
  hipLaunchKernelGGL(k_raw, dim3(GE), dim3(TPB), 0, stream, h1out, src, dst, (const unsigned char*)nullptr, Wp1, bp1, raw, mEnc, HH);
  hipLaunchKernelGGL(k_exps, dim3(GE), dim3(TPB), 0, stream, raw, dst, (const unsigned char*)nullptr, mEnc, ex, ssum);
  hipLaunchKernelGGL(k_score, dim3(GE), dim3(TPB), 0, stream, ex, dst, (const unsigned char*)nullptr, ssum, score);
  hipMemsetAsync(rem, 1, NN, stream);
  hipMemsetAsync(chosen, 0, EE, stream);
  {
    const int* p0 = src; const int* p1 = dst; const float* p2 = score;
    const unsigned char* p3 = nullptr;
    unsigned char* p4 = rem; unsigned char* p5 = chosen;
    unsigned long long* p6 = best; int* p7 = elist0; int* p8 = elist1; int* p9 = cnts;
    void* margs[10] = {&p0, &p1, &p2, &p3, &p4, &p5, &p6, &p7, &p8, &p9};
    hipLaunchCooperativeKernel(reinterpret_cast<const void*>(&k_match), dim3(256), dim3(TPB), margs, 0, stream);
  }
  hipMemsetAsync(added, 0, (size_t)NN * CC * 4, stream);
  hipMemsetAsync(merged, 0xFF, (size_t)NN * 4, stream);
  hipLaunchKernelGGL(k_pool_node, dim3(GN), dim3(TPB), 0, stream, (const unsigned char*)nullptr, nv1, scale);
  hipLaunchKernelGGL(k_pool_edge, dim3(GE), dim3(TPB), 0, stream, src, dst, chosen, score, h1out, nv1, scale, added, merged, HH);
  hipLaunchKernelGGL(k_newx, dim3(GN), dim3(TPB), 0, stream, h1out, added, scale, nv1, newx1, HH);
  hipLaunchKernelGGL(k_cmap, dim3(GN), dim3(TPB), 0, stream, merged, cmap);
  hipLaunchKernelGGL(k_remap, dim3(GE), dim3(TPB), 0, stream, src, dst, cmap, ns, nd);
  hipMemsetAsync(htab, 0xFF, (size_t)HT_SIZE * 8, stream);
  hipLaunchKernelGGL(k_dedup_ins, dim3(GE), dim3(TPB), 0, stream, ns, nd, htab);
  hipLaunchKernelGGL(k_dedup_mark, dim3(GE), dim3(TPB), 0, stream, ns, nd, htab, ev1);

  // ===== stage 2: GCNConv(6->10) =====
  hipLaunchKernelGGL(k_mm2, dim3(GN), dim3(TPB), 0, stream, newx1, W2, h2pre);
  hipMemsetAsync(deg, 0, (size_t)NN * 4, stream);
  hipMemsetAsync(hasloop, 0, NN, stream);
  hipMemsetAsync(h2out, 0, (size_t)NN * CC * 4, stream);
  hipLaunchKernelGGL(k_deg, dim3(GE), dim3(TPB), 0, stream, ns, nd, (const unsigned char*)ev1, deg, hasloop);
  hipLaunchKernelGGL(k_dinv, dim3(GN), dim3(TPB), 0, stream, deg, hasloop, (const unsigned char*)nv1, dinv, addloop);
  hipLaunchKernelGGL(k_gcn_agg, dim3(GE), dim3(TPB), 0, stream, ns, nd, (const unsigned char*)ev1, dinv, h2pre, h2out, CC);
  hipLaunchKernelGGL(k_gcn_fin, dim3(GN), dim3(TPB), 0, stream, h2pre, dinv, addloop, b2, h2out, CC, 0);

  // ===== edge pool 2 (no remap/dedup needed) =====
  hipMemsetAsync(mEnc, 0, (size_t)NN * 4, stream);
  hipMemsetAsync(ssum, 0, (size_t)NN * 4, stream);
  hipLaunchKernelGGL(k_raw, dim3(GE), dim3(TPB), 0, stream, h2out, ns, nd, (const unsigned char*)ev1, Wp2, bp2, raw, mEnc, CC);
  hipLaunchKernelGGL(k_exps, dim3(GE), dim3(TPB), 0, stream, raw, nd, (const unsigned char*)ev1, mEnc, ex, ssum);
  hipLaunchKernelGGL(k_score, dim3(GE), dim3(TPB), 0, stream, ex, nd, (const unsigned char*)ev1, ssum, score);
  hipLaunchKernelGGL(k_copy_u8, dim3(GN), dim3(TPB), 0, stream, nv1, rem, NN);
  hipMemsetAsync(chosen, 0, EE, stream);
  {
    const int* p0 = ns; const int* p1 = nd; const float* p2 = score;
    const unsigned char* p3 = ev1;
    unsigned char* p4 = rem; unsigned char* p5 = chosen;
    unsigned long long* p6 = best; int* p7 = elist0; int* p8 = elist1; int* p9 = cnts;
    void* margs[10] = {&p0, &p1, &p2, &p3, &p4, &p5, &p6, &p7, &p8, &p9};
    hipLaunchCooperativeKernel(reinterpret_cast<const void*>(&k_match), dim3(256), dim3(TPB), margs, 0, stream);
  }
  hipMemsetAsync(added, 0, (size_t)NN * CC * 4, stream);
  hipLaunchKernelGGL(k_pool_node, dim3(GN), dim3(TPB), 0, stream, (const unsigned char*)nv1, nv2, scale);
  hipLaunchKernelGGL(k_pool_edge, dim3(GE), dim3(TPB), 0, stream, ns, nd, chosen, score, h2out, nv2, scale, added, (int*)nullptr, CC);
  hipLaunchKernelGGL(k_newx, dim3(GN), dim3(TPB), 0, stream, h2out, added, scale, nv2, newx2, CC);

  // ===== readout =====
  hipMemsetAsync(gsum, 0, (size_t)BB * CC * 4, stream);
  hipMemsetAsync(gcnt, 0, (size_t)BB * 4, stream);
  hipLaunchKernelGGL(k_graphpool, dim3(GN), dim3(TPB), 0, stream, newx2, nv2, batch, gsum, gcnt);
  hipLaunchKernelGGL(k_logsm, dim3(1), dim3(64), 0, stream, gsum, gcnt, out);
}

// Round 2
// 5170.033 us; speedup vs baseline: 1.8242x; 1.8242x over previous
//
#include <hip/hip_runtime.h>
#include <hip/hip_cooperative_groups.h>
#include <math.h>

namespace cg = cooperative_groups;

#define NN 60000
#define BB 8
#define FF 384
#define EE 600000
#define HH 6
#define CC 10
#define HT_BITS 20
#define HT_SIZE (1u << HT_BITS)
#define HT_MASK (HT_SIZE - 1u)
#define TPB 256
#define TAIL 4096
#define REMW 1875  // 60000/32

static inline int ngrid(int n) { return (n + TPB - 1) / TPB; }

// ---------- helpers ----------
__device__ __forceinline__ unsigned int encf(float v) {
  unsigned int b = __float_as_uint(v);
  return (b & 0x80000000u) ? ~b : (b | 0x80000000u);
}
__device__ __forceinline__ float decf(unsigned int u) {
  unsigned int b = (u & 0x80000000u) ? (u & 0x7FFFFFFFu) : ~u;
  return __uint_as_float(b);
}
__device__ __forceinline__ unsigned long long prio(const float* score, int e) {
  return (((unsigned long long)__float_as_uint(score[e])) << 32) |
         (unsigned int)(~(unsigned int)e);
}

// ---------- stage 1 matmul: h1pre = x @ W1 (N x 384 @ 384 x 6) ----------
__global__ void k_mm1(const float* __restrict__ x, const float* __restrict__ W,
                      float* __restrict__ out) {
  __shared__ float Ws[FF * HH];
  for (int i = threadIdx.x; i < FF * HH; i += blockDim.x) Ws[i] = W[i];
  __syncthreads();
  int wave = threadIdx.x >> 6, lane = threadIdx.x & 63;
  int node = blockIdx.x * 4 + wave;
  if (node >= NN) return;
  const float* xr = x + (size_t)node * FF;
  float acc[HH] = {0.f, 0.f, 0.f, 0.f, 0.f, 0.f};
  for (int k = lane; k < FF; k += 64) {
    float xv = xr[k];
#pragma unroll
    for (int j = 0; j < HH; j++) acc[j] += xv * Ws[k * HH + j];
  }
#pragma unroll
  for (int j = 0; j < HH; j++) {
#pragma unroll
    for (int o = 32; o > 0; o >>= 1) acc[j] += __shfl_down(acc[j], o, 64);
  }
  if (lane == 0) {
#pragma unroll
    for (int j = 0; j < HH; j++) out[(size_t)node * HH + j] = acc[j];
  }
}

// ---------- stage 2 matmul: h2pre = newx1 @ W2 (N x 6 @ 6 x 10) ----------
__global__ void k_mm2(const float* __restrict__ x, const float* __restrict__ W,
                      float* __restrict__ out) {
  int v = blockIdx.x * blockDim.x + threadIdx.x;
  if (v >= NN) return;
  float xv[HH];
#pragma unroll
  for (int j = 0; j < HH; j++) xv[j] = x[(size_t)v * HH + j];
#pragma unroll
  for (int c = 0; c < CC; c++) {
    float a = 0.f;
#pragma unroll
    for (int j = 0; j < HH; j++) a += xv[j] * W[j * CC + c];
    out[(size_t)v * CC + c] = a;
  }
}

// ---------- generic GCN conv pieces ----------
__global__ void k_deg(const int* __restrict__ src, const int* __restrict__ dst,
                      const unsigned char* __restrict__ ev, float* __restrict__ deg,
                      unsigned char* __restrict__ hasloop) {
  int e = blockIdx.x * blockDim.x + threadIdx.x;
  if (e >= EE) return;
  if (ev && !ev[e]) return;
  int d = dst[e];
  atomicAdd(&deg[d], 1.0f);
  if (src[e] == d) hasloop[d] = 1;
}

__global__ void k_dinv(const float* __restrict__ deg, const unsigned char* __restrict__ hasloop,
                       const unsigned char* __restrict__ nv, float* __restrict__ dinv,
                       unsigned char* __restrict__ addloop) {
  int v = blockIdx.x * blockDim.x + threadIdx.x;
  if (v >= NN) return;
  int nvv = nv ? (int)nv[v] : 1;
  unsigned char al = (nvv && !hasloop[v]) ? 1 : 0;
  float d = deg[v] + (float)al;
  dinv[v] = d > 0.f ? 1.0f / sqrtf(fmaxf(d, 1e-12f)) : 0.f;
  addloop[v] = al;
}

__global__ void k_gcn_agg(const int* __restrict__ src, const int* __restrict__ dst,
                          const unsigned char* __restrict__ ev, const float* __restrict__ dinv,
                          const float* __restrict__ h, float* __restrict__ out, int fd) {
  int e = blockIdx.x * blockDim.x + threadIdx.x;
  if (e >= EE) return;
  if (ev && !ev[e]) return;
  int s = src[e], d = dst[e];
  float c = dinv[s] * dinv[d];
  for (int j = 0; j < fd; j++)
    atomicAdd(&out[(size_t)d * fd + j], h[(size_t)s * fd + j] * c);
}

__global__ void k_gcn_fin(const float* __restrict__ h, const float* __restrict__ dinv,
                          const unsigned char* __restrict__ addloop, const float* __restrict__ b,
                          float* __restrict__ out, int fd, int relu) {
  int v = blockIdx.x * blockDim.x + threadIdx.x;
  if (v >= NN) return;
  float c = addloop[v] ? dinv[v] * dinv[v] : 0.f;
  for (int j = 0; j < fd; j++) {
    float o = out[(size_t)v * fd + j] + c * h[(size_t)v * fd + j] + b[j];
    if (relu) o = fmaxf(o, 0.f);
    out[(size_t)v * fd + j] = o;
  }
}

// ---------- edge pool: scores ----------
__global__ void k_raw(const float* __restrict__ x, const int* __restrict__ src,
                      const int* __restrict__ dst, const unsigned char* __restrict__ ev,
                      const float* __restrict__ Wp, const float* __restrict__ bp,
                      float* __restrict__ raw, unsigned int* __restrict__ mEnc, int fd) {
  int e = blockIdx.x * blockDim.x + threadIdx.x;
  if (e >= EE) return;
  if (ev && !ev[e]) return;
  int s = src[e], d = dst[e];
  float r = bp[0];
  for (int j = 0; j < fd; j++) r += x[(size_t)s * fd + j] * Wp[j];
  for (int j = 0; j < fd; j++) r += x[(size_t)d * fd + j] * Wp[fd + j];
  raw[e] = r;
  atomicMax(&mEnc[d], encf(r));
}

__global__ void k_exps(const float* __restrict__ raw, const int* __restrict__ dst,
                       const unsigned char* __restrict__ ev, const unsigned int* __restrict__ mEnc,
                       float* __restrict__ ex, float* __restrict__ ssum) {
  int e = blockIdx.x * blockDim.x + threadIdx.x;
  if (e >= EE) return;
  if (ev && !ev[e]) return;
  int d = dst[e];
  unsigned int me = mEnc[d];
  float m = me ? decf(me) : 0.f;
  float v = expf(raw[e] - m);
  ex[e] = v;
  atomicAdd(&ssum[d], v);
}

__global__ void k_score(const float* __restrict__ ex, const int* __restrict__ dst,
                        const unsigned char* __restrict__ ev, const float* __restrict__ ssum,
                        float* __restrict__ score) {
  int e = blockIdx.x * blockDim.x + threadIdx.x;
  if (e >= EE) return;
  if (ev && !ev[e]) return;
  float sd = ssum[dst[e]];
  score[e] = ex[e] / (sd > 0.f ? sd : 1.0f) + 0.5f;
}

// ---------- matching: locally-dominant greedy (== sequential greedy) ----------
// Grid phase: 2 syncs/round via double-buffered best[]; once n <= TAIL,
// block 0 sorts survivors by exact priority and runs sequential greedy
// with wave-parallel 64-edge chunks (order-exact continuation).
__global__ void k_match(const int* __restrict__ src, const int* __restrict__ dst,
                        const float* __restrict__ score, const unsigned char* __restrict__ evalid,
                        unsigned char* __restrict__ rem, unsigned char* __restrict__ chosen,
                        unsigned long long* __restrict__ best0,
                        unsigned long long* __restrict__ best1,
                        int* __restrict__ elist0, int* __restrict__ elist1,
                        int* __restrict__ cnts) {
  cg::grid_group g = cg::this_grid();
  int nt = gridDim.x * blockDim.x;
  int tid = blockIdx.x * blockDim.x + threadIdx.x;
  int lane = threadIdx.x & 63;

  if (tid == 0) { cnts[0] = 0; cnts[1] = 0; }
  g.sync();
  // build initial list of valid edges (wave-aggregated append); zero best0
  for (int e = tid; e < EE; e += nt) {
    int ok = evalid ? (evalid[e] ? 1 : 0) : 1;
    if (ok) { best0[src[e]] = 0ULL; best0[dst[e]] = 0ULL; }
    unsigned long long m = __ballot(ok);
    int tot = __popcll(m);
    int pre = __popcll(m & ((1ULL << lane) - 1ULL));
    int base = 0;
    if (lane == 0 && tot) base = atomicAdd(&cnts[0], tot);
    base = __shfl(base, 0, 64);
    if (ok) elist0[base + pre] = e;
  }
  __threadfence();
  g.sync();

  int cur = 0;
  int* lists[2] = {elist0, elist1};
  unsigned long long* bests[2] = {best0, best1};
  int n = 0;
  for (int round = 0; round < 100000; round++) {
    n = *(volatile int*)&cnts[cur];
    if (n <= TAIL) break;
    if (tid == 0) cnts[cur ^ 1] = 0;
    // P1: post priorities into current best buffer
    for (int i = tid; i < n; i += nt) {
      int e = lists[cur][i];
      int s = src[e], d = dst[e];
      if (!rem[s] || !rem[d]) continue;
      unsigned long long p = prio(score, e);
      atomicMax(&bests[cur][s], p);
      if (d != s) atomicMax(&bests[cur][d], p);
    }
    __threadfence();
    g.sync();
    // P2: select winners; survivors compact + zero NEXT best buffer
    for (int i = tid; i < n; i += nt) {
      int e = lists[cur][i];
      int s = src[e], d = dst[e];
      int keep = 0;
      if (rem[s] && rem[d]) {
        unsigned long long p = prio(score, e);
        if (bests[cur][s] == p && bests[cur][d] == p) {
          chosen[e] = 1;
          rem[s] = 0;
          rem[d] = 0;
        } else {
          keep = 1;
          bests[cur ^ 1][s] = 0ULL;
          bests[cur ^ 1][d] = 0ULL;
        }
      }
      unsigned long long m = __ballot(keep);
      int tot = __popcll(m);
      int pre = __popcll(m & ((1ULL << lane) - 1ULL));
      int base = 0;
      if (lane == 0 && tot) base = atomicAdd(&cnts[cur ^ 1], tot);
      base = __shfl(base, 0, 64);
      if (keep) lists[cur ^ 1][base + pre] = e;
    }
    __threadfence();
    g.sync();
    cur ^= 1;
  }

  // ---- tail: single block, exact sequential greedy over sorted survivors
  if (blockIdx.x != 0 || n == 0) return;
  __shared__ unsigned long long keys[TAIL];
  __shared__ unsigned int remBits[REMW];
  int t = threadIdx.x, nth = blockDim.x;
  for (int w = t; w < REMW; w += nth) {
    unsigned int bits = 0;
    for (int b = 0; b < 32; b++) bits |= (rem[w * 32 + b] ? 1u : 0u) << b;
    remBits[w] = bits;
  }
  int np = 1;
  while (np < n) np <<= 1;
  const int* lst = lists[cur];
  for (int i = t; i < np; i += nth)
    keys[i] = (i < n) ? prio(score, lst[i]) : 0ULL;
  __syncthreads();
  // bitonic sort, descending
  for (int k = 2; k <= np; k <<= 1) {
    for (int j = k >> 1; j >= 1; j >>= 1) {
      for (int i = t; i < np; i += nth) {
        int ixj = i ^ j;
        if (ixj > i) {
          unsigned long long a = keys[i], b = keys[ixj];
          bool desc = ((i & k) == 0);
          if (desc ? (a < b) : (a > b)) { keys[i] = b; keys[ixj] = a; }
        }
      }
      __syncthreads();
    }
  }
  if (t >= 64) return;
  // wave 0: sequential greedy in 64-edge chunks
  for (int c0 = 0; c0 < n; c0 += 64) {
    int idx = c0 + lane;
    unsigned long long p = (idx < n) ? keys[idx] : 0ULL;
    int e = (int)(~(unsigned int)p);
    int alive = 0, s = 0, d = 0;
    if (p) {
      s = src[e];
      d = dst[e];
      alive = ((remBits[s >> 5] >> (s & 31)) & 1u) && ((remBits[d >> 5] >> (d & 31)) & 1u);
    }
    unsigned long long am = __ballot(alive);
    for (int i = 0; i < 64; i++) {
      if (!((am >> i) & 1ULL)) continue;
      int si = __shfl(s, i, 64), di = __shfl(d, i, 64);
      if (lane > i && alive && (s == si || s == di || d == si || d == di)) alive = 0;
      am = __ballot(alive);
    }
    if (alive) {
      chosen[e] = 1;
      atomicAnd(&remBits[s >> 5], ~(1u << (s & 31)));
      atomicAnd(&remBits[d >> 5], ~(1u << (d & 31)));
    }
  }
}

// ---------- edge pool: post-matching ----------
__global__ void k_pool_node(const unsigned char* __restrict__ nvin, unsigned char* __restrict__ nvout,
                            float* __restrict__ scale) {
  int v = blockIdx.x * blockDim.x + threadIdx.x;
  if (v >= NN) return;
  nvout[v] = nvin ? nvin[v] : 1;
  scale[v] = 1.0f;
}

__global__ void k_pool_edge(const int* __restrict__ src, const int* __restrict__ dst,
                            const unsigned char* __restrict__ chosen, const float* __restrict__ score,
                            const float* __restrict__ x, unsigned char* __restrict__ nvout,
                            float* __restrict__ scale, float* __restrict__ added,
                            int* __restrict__ merged, int fd) {
  int e = blockIdx.x * blockDim.x + threadIdx.x;
  if (e >= EE) return;
  if (!chosen[e]) return;
  int s = src[e], d = dst[e];
  scale[s] = score[e];
  if (merged) merged[d] = s;
  if (s != d) {
    nvout[d] = 0;
    for (int j = 0; j < fd; j++) added[(size_t)s * fd + j] = x[(size_t)d * fd + j];
  }
}

__global__ void k_newx(const float* __restrict__ x, const float* __restrict__ added,
                       const float* __restrict__ scale, const unsigned char* __restrict__ nvout,
                       float* __restrict__ newx, int fd) {
  int v = blockIdx.x * blockDim.x + threadIdx.x;
  if (v >= NN) return;
  float sc = scale[v];
  int ok = nvout[v];
  for (int j = 0; j < fd; j++)
    newx[(size_t)v * fd + j] =
        ok ? (x[(size_t)v * fd + j] + added[(size_t)v * fd + j]) * sc : 0.f;
}

__global__ void k_cmap(const int* __restrict__ merged, int* __restrict__ cmap) {
  int v = blockIdx.x * blockDim.x + threadIdx.x;
  if (v >= NN) return;
  int m = merged[v];
  cmap[v] = m >= 0 ? m : v;
}

__global__ void k_remap(const int* __restrict__ src, const int* __restrict__ dst,
                        const int* __restrict__ cmap, int* __restrict__ ns, int* __restrict__ nd) {
  int e = blockIdx.x * blockDim.x + threadIdx.x;
  if (e >= EE) return;
  ns[e] = cmap[src[e]];
  nd[e] = cmap[dst[e]];
}

// ---------- dedup via hash: keep min original index per (ns,nd) ----------
__device__ __forceinline__ unsigned int ht_hash(unsigned long long key) {
  return (unsigned int)((key * 0x9E3779B97F4A7C15ULL) >> 44) & HT_MASK;
}

__global__ void k_dedup_ins(const int* __restrict__ ns, const int* __restrict__ nd,
                            unsigned long long* __restrict__ htab) {
  int e = blockIdx.x * blockDim.x + threadIdx.x;
  if (e >= EE) return;
  unsigned long long key =
      (unsigned long long)((((unsigned int)ns[e]) << 16) | (unsigned int)nd[e]);
  unsigned long long val = (key << 32) | (unsigned int)e;
  unsigned int h = ht_hash(key);
  for (;;) {
    unsigned long long curv = htab[h];
    if (curv == ~0ULL) {
      unsigned long long prev = atomicCAS(&htab[h], ~0ULL, val);
      if (prev == ~0ULL) break;
      curv = prev;
    }
    if ((curv >> 32) == key) {
      atomicMin(&htab[h], val);
      break;
    }
    h = (h + 1) & HT_MASK;
  }
}

__global__ void k_dedup_mark(const int* __restrict__ ns, const int* __restrict__ nd,
                             const unsigned long long* __restrict__ htab,
                             unsigned char* __restrict__ evout) {
  int e = blockIdx.x * blockDim.x + threadIdx.x;
  if (e >= EE) return;
  unsigned long long key =
      (unsigned long long)((((unsigned int)ns[e]) << 16) | (unsigned int)nd[e]);
  unsigned int h = ht_hash(key);
  for (;;) {
    unsigned long long curv = htab[h];
    if ((curv >> 32) == key) {
      evout[e] = ((curv & 0xFFFFFFFFULL) == (unsigned long long)(unsigned int)e) ? 1 : 0;
      return;
    }
    h = (h + 1) & HT_MASK;
  }
}

// ---------- misc ----------
__global__ void k_copy_u8(const unsigned char* __restrict__ a, unsigned char* __restrict__ b, int n) {
  int i = blockIdx.x * blockDim.x + threadIdx.x;
  if (i < n) b[i] = a[i];
}

__global__ void k_graphpool(const float* __restrict__ h, const unsigned char* __restrict__ nv,
                            const int* __restrict__ batch, float* __restrict__ gsum,
                            float* __restrict__ gcnt) {
  int v = blockIdx.x * blockDim.x + threadIdx.x;
  int lane = threadIdx.x & 63;
  int vc = v < NN ? v : NN - 1;
  int b = batch[vc];
  int active = (v < NN) && nv[v];
  float cnt = active ? 1.f : 0.f;
  float val[CC];
  for (int j = 0; j < CC; j++) val[j] = active ? h[(size_t)v * CC + j] : 0.f;
  int b0 = __shfl(b, 0, 64);
  unsigned long long same = __ballot(b == b0);
  if (same == ~0ULL) {
    for (int o = 32; o > 0; o >>= 1) {
      cnt += __shfl_down(cnt, o, 64);
      for (int j = 0; j < CC; j++) val[j] += __shfl_down(val[j], o, 64);
    }
    if (lane == 0 && cnt > 0.f) {
      atomicAdd(&gcnt[b0], cnt);
      for (int j = 0; j < CC; j++) atomicAdd(&gsum[b0 * CC + j], val[j]);
    }
  } else if (active) {
    atomicAdd(&gcnt[b], cnt);
    for (int j = 0; j < CC; j++) atomicAdd(&gsum[b * CC + j], val[j]);
  }
}

__global__ void k_logsm(const float* __restrict__ gsum, const float* __restrict__ gcnt,
                        float* __restrict__ out) {
  int t = threadIdx.x;
  if (t >= BB) return;
  float gr[CC];
  float c = gcnt[t];
  float m = -INFINITY;
  for (int j = 0; j < CC; j++) {
    gr[j] = gsum[t * CC + j] / c;
    m = fmaxf(m, gr[j]);
  }
  float s = 0.f;
  for (int j = 0; j < CC; j++) s += expf(gr[j] - m);
  float l = logf(s);
  for (int j = 0; j < CC; j++) out[t * CC + j] = gr[j] - m - l;
}

// ---------- host ----------
extern "C" void kernel_launch(void* const* d_in, const int* in_sizes, int n_in,
                              void* d_out, int out_size, void* d_ws, size_t ws_size,
                              hipStream_t stream) {
  const float* x = (const float*)d_in[0];
  const int* src = (const int*)d_in[1];
  const int* dst = (const int*)d_in[2];
  const int* batch = (const int*)d_in[3];
  const float* W1 = (const float*)d_in[4];
  const float* b1 = (const float*)d_in[5];
  const float* W2 = (const float*)d_in[6];
  const float* b2 = (const float*)d_in[7];
  const float* Wp1 = (const float*)d_in[8];
  const float* bp1 = (const float*)d_in[9];
  const float* Wp2 = (const float*)d_in[10];
  const float* bp2 = (const float*)d_in[11];
  float* out = (float*)d_out;

  char* wsb = (char*)d_ws;
  size_t off = 0;
  auto A = [&](size_t bytes) -> char* {
    char* r = wsb + off;
    off = (off + bytes + 255) & ~(size_t)255;
    return r;
  };
  float* h1pre = (float*)A((size_t)NN * HH * 4);
  float* h1out = (float*)A((size_t)NN * HH * 4);
  float* deg = (float*)A((size_t)NN * 4);
  float* dinv = (float*)A((size_t)NN * 4);
  unsigned char* hasloop = (unsigned char*)A(NN);
  unsigned char* addloop = (unsigned char*)A(NN);
  float* raw = (float*)A((size_t)EE * 4);
  float* ex = (float*)A((size_t)EE * 4);
  float* score = (float*)A((size_t)EE * 4);
  unsigned int* mEnc = (unsigned int*)A((size_t)NN * 4);
  float* ssum = (float*)A((size_t)NN * 4);
  unsigned long long* best0 = (unsigned long long*)A((size_t)NN * 8);
  unsigned long long* best1 = (unsigned long long*)A((size_t)NN * 8);
  unsigned char* rem = (unsigned char*)A(NN);
  unsigned char* chosen = (unsigned char*)A(EE);
  unsigned char* nv1 = (unsigned char*)A(NN);
  unsigned char* nv2 = (unsigned char*)A(NN);
  float* scale = (float*)A((size_t)NN * 4);
  float* added = (float*)A((size_t)NN * CC * 4);
  float* newx1 = (float*)A((size_t)NN * HH * 4);
  int* merged = (int*)A((size_t)NN * 4);
  int* cmap = (int*)A((size_t)NN * 4);
  int* ns = (int*)A((size_t)EE * 4);
  int* nd = (int*)A((size_t)EE * 4);
  unsigned char* ev1 = (unsigned char*)A(EE);
  unsigned long long* htab = (unsigned long long*)A((size_t)HT_SIZE * 8);
  float* h2pre = (float*)A((size_t)NN * CC * 4);
  float* h2out = (float*)A((size_t)NN * CC * 4);
  float* newx2 = (float*)A((size_t)NN * CC * 4);
  int* elist0 = (int*)A((size_t)EE * 4);
  int* elist1 = (int*)A((size_t)EE * 4);
  int* cnts = (int*)A(64);
  float* gsum = (float*)A((size_t)BB * CC * 4);
  float* gcnt = (float*)A((size_t)BB * 4);
  (void)ws_size; (void)n_in; (void)in_sizes; (void)out_size;

  const int GE = ngrid(EE), GN = ngrid(NN);
  const int MATCH_BLOCKS = 128;

  // ===== stage 1: GCNConv(384->6) + ReLU =====
  hipLaunchKernelGGL(k_mm1, dim3((NN + 3) / 4), dim3(TPB), 0, stream, x, W1, h1pre);
  hipMemsetAsync(deg, 0, (size_t)NN * 4, stream);
  hipMemsetAsync(hasloop, 0, NN, stream);
  hipMemsetAsync(h1out, 0, (size_t)NN * HH * 4, stream);
  hipLaunchKernelGGL(k_deg, dim3(GE), dim3(TPB), 0, stream, src, dst, (const unsigned char*)nullptr, deg, hasloop);
  hipLaunchKernelGGL(k_dinv, dim3(GN), dim3(TPB), 0, stream, deg, hasloop, (const unsigned char*)nullptr, dinv, addloop);
  hipLaunchKernelGGL(k_gcn_agg, dim3(GE), dim3(TPB), 0, stream, src, dst, (const unsigned char*)nullptr, dinv, h1pre, h1out, HH);
  hipLaunchKernelGGL(k_gcn_fin, dim3(GN), dim3(TPB), 0, stream, h1pre, dinv, addloop, b1, h1out, HH, 1);

  // ===== edge pool 1 =====
  hipMemsetAsync(mEnc, 0, (size_t)NN * 4, stream);
  hipMemsetAsync(ssum, 0, (size_t)NN * 4, stream);
  hipLaunchKernelGGL(k_raw, dim3(GE), dim3(TPB), 0, stream, h1out, src, dst, (const unsigned char*)nullptr, Wp1, bp1, raw, mEnc, HH);
  hipLaunchKernelGGL(k_exps, dim3(GE), dim3(TPB), 0, stream, raw, dst, (const unsigned char*)nullptr, mEnc, ex, ssum);
  hipLaunchKernelGGL(k_score, dim3(GE), dim3(TPB), 0, stream, ex, dst, (const unsigned char*)nullptr, ssum, score);
  hipMemsetAsync(rem, 1, NN, stream);
  hipMemsetAsync(chosen, 0, EE, stream);
  {
    const int* p0 = src; const int* p1 = dst; const float* p2 = score;
    const unsigned char* p3 = nullptr;
    unsigned char* p4 = rem; unsigned char* p5 = chosen;
    unsigned long long* p6 = best0; unsigned long long* p7 = best1;
    int* p8 = elist0; int* p9 = elist1; int* p10 = cnts;
    void* margs[11] = {&p0, &p1, &p2, &p3, &p4, &p5, &p6, &p7, &p8, &p9, &p10};
    hipLaunchCooperativeKernel(reinterpret_cast<const void*>(&k_match), dim3(MATCH_BLOCKS), dim3(TPB), margs, 0, stream);
  }
  hipMemsetAsync(added, 0, (size_t)NN * CC * 4, stream);
  hipMemsetAsync(merged, 0xFF, (size_t)NN * 4, stream);
  hipLaunchKernelGGL(k_pool_node, dim3(GN), dim3(TPB), 0, stream, (const unsigned char*)nullptr, nv1, scale);
  hipLaunchKernelGGL(k_pool_edge, dim3(GE), dim3(TPB), 0, stream, src, dst, chosen, score, h1out, nv1, scale, added, merged, HH);
  hipLaunchKernelGGL(k_newx, dim3(GN), dim3(TPB), 0, stream, h1out, added, scale, nv1, newx1, HH);
  hipLaunchKernelGGL(k_cmap, dim3(GN), dim3(TPB), 0, stream, merged, cmap);
  hipLaunchKernelGGL(k_remap, dim3(GE), dim3(TPB), 0, stream, src, dst, cmap, ns, nd);
  hipMemsetAsync(htab, 0xFF, (size_t)HT_SIZE * 8, stream);
  hipLaunchKernelGGL(k_dedup_ins, dim3(GE), dim3(TPB), 0, stream, ns, nd, htab);
  hipLaunchKernelGGL(k_dedup_mark, dim3(GE), dim3(TPB), 0, stream, ns, nd, htab, ev1);

  // ===== stage 2: GCNConv(6->10) =====
  hipLaunchKernelGGL(k_mm2, dim3(GN), dim3(TPB), 0, stream, newx1, W2, h2pre);
  hipMemsetAsync(deg, 0, (size_t)NN * 4, stream);
  hipMemsetAsync(hasloop, 0, NN, stream);
  hipMemsetAsync(h2out, 0, (size_t)NN * CC * 4, stream);
  hipLaunchKernelGGL(k_deg, dim3(GE), dim3(TPB), 0, stream, ns, nd, (const unsigned char*)ev1, deg, hasloop);
  hipLaunchKernelGGL(k_dinv, dim3(GN), dim3(TPB), 0, stream, deg, hasloop, (const unsigned char*)nv1, dinv, addloop);
  hipLaunchKernelGGL(k_gcn_agg, dim3(GE), dim3(TPB), 0, stream, ns, nd, (const unsigned char*)ev1, dinv, h2pre, h2out, CC);
  hipLaunchKernelGGL(k_gcn_fin, dim3(GN), dim3(TPB), 0, stream, h2pre, dinv, addloop, b2, h2out, CC, 0);

  // ===== edge pool 2 (no remap/dedup needed) =====
  hipMemsetAsync(mEnc, 0, (size_t)NN * 4, stream);
  hipMemsetAsync(ssum, 0, (size_t)NN * 4, stream);
  hipLaunchKernelGGL(k_raw, dim3(GE), dim3(TPB), 0, stream, h2out, ns, nd, (const unsigned char*)ev1, Wp2, bp2, raw, mEnc, CC);
  hipLaunchKernelGGL(k_exps, dim3(GE), dim3(TPB), 0, stream, raw, nd, (const unsigned char*)ev1, mEnc, ex, ssum);
  hipLaunchKernelGGL(k_score, dim3(GE), dim3(TPB), 0, stream, ex, nd, (const unsigned char*)ev1, ssum, score);
  hipLaunchKernelGGL(k_copy_u8, dim3(GN), dim3(TPB), 0, stream, nv1, rem, NN);
  hipMemsetAsync(chosen, 0, EE, stream);
  {
    const int* p0 = ns; const int* p1 = nd; const float* p2 = score;
    const unsigned char* p3 = ev1;
    unsigned char* p4 = rem; unsigned char* p5 = chosen;
    unsigned long long* p6 = best0; unsigned long long* p7 = best1;
    int* p8 = elist0; int* p9 = elist1; int* p10 = cnts;
    void* margs[11] = {&p0, &p1, &p2, &p3, &p4, &p5, &p6, &p7, &p8, &p9, &p10};
    hipLaunchCooperativeKernel(reinterpret_cast<const void*>(&k_match), dim3(MATCH_BLOCKS), dim3(TPB), margs, 0, stream);
  }
  hipMemsetAsync(added, 0, (size_t)NN * CC * 4, stream);
  hipLaunchKernelGGL(k_pool_node, dim3(GN), dim3(TPB), 0, stream, (const unsigned char*)nv1, nv2, scale);
  hipLaunchKernelGGL(k_pool_edge, dim3(GE), dim3(TPB), 0, stream, ns, nd, chosen, score, h2out, nv2, scale, added, (int*)nullptr, CC);
  hipLaunchKernelGGL(k_newx, dim3(GN), dim3(TPB), 0, stream, h2out, added, scale, nv2, newx2, CC);

  // ===== readout =====
  hipMemsetAsync(gsum, 0, (size_t)BB * CC * 4, stream);
  hipMemsetAsync(gcnt, 0, (size_t)BB * 4, stream);
  hipLaunchKernelGGL(k_graphpool, dim3(GN), dim3(TPB), 0, stream, newx2, nv2, batch, gsum, gcnt);
  hipLaunchKernelGGL(k_logsm, dim3(1), dim3(64), 0, stream, gsum, gcnt, out);
}

// Round 3
// 3633.512 us; speedup vs baseline: 2.5956x; 1.4229x over previous
//
#include <hip/hip_runtime.h>
#include <math.h>

#define NN 60000
#define BB 8
#define GS 7500   // nodes per graph
#define FF 384
#define EE 600000
#define HH 6
#define CC 10
#define HT_BITS 20
#define HT_SIZE (1u << HT_BITS)
#define HT_MASK (HT_SIZE - 1u)
#define TPB 256
#define CAP 80000  // per-graph edge capacity (mean 75000, sigma ~256)
#define REMW ((GS + 31) / 32)

static inline int ngrid(int n) { return (n + TPB - 1) / TPB; }

// ---------- helpers ----------
__device__ __forceinline__ unsigned int encf(float v) {
  unsigned int b = __float_as_uint(v);
  return (b & 0x80000000u) ? ~b : (b | 0x80000000u);
}
__device__ __forceinline__ float decf(unsigned int u) {
  unsigned int b = (u & 0x80000000u) ? (u & 0x7FFFFFFFu) : ~u;
  return __uint_as_float(b);
}

// ---------- stage 1 matmul: h1pre = x @ W1 (N x 384 @ 384 x 6) ----------
__global__ void k_mm1(const float* __restrict__ x, const float* __restrict__ W,
                      float* __restrict__ out) {
  __shared__ float Ws[FF * HH];
  for (int i = threadIdx.x; i < FF * HH; i += blockDim.x) Ws[i] = W[i];
  __syncthreads();
  int wave = threadIdx.x >> 6, lane = threadIdx.x & 63;
  int node = blockIdx.x * 4 + wave;
  if (node >= NN) return;
  const float* xr = x + (size_t)node * FF;
  float acc[HH] = {0.f, 0.f, 0.f, 0.f, 0.f, 0.f};
  for (int k = lane; k < FF; k += 64) {
    float xv = xr[k];
#pragma unroll
    for (int j = 0; j < HH; j++) acc[j] += xv * Ws[k * HH + j];
  }
#pragma unroll
  for (int j = 0; j < HH; j++) {
#pragma unroll
    for (int o = 32; o > 0; o >>= 1) acc[j] += __shfl_down(acc[j], o, 64);
  }
  if (lane == 0) {
#pragma unroll
    for (int j = 0; j < HH; j++) out[(size_t)node * HH + j] = acc[j];
  }
}

// ---------- stage 2 matmul: h2pre = newx1 @ W2 (N x 6 @ 6 x 10) ----------
__global__ void k_mm2(const float* __restrict__ x, const float* __restrict__ W,
                      float* __restrict__ out) {
  int v = blockIdx.x * blockDim.x + threadIdx.x;
  if (v >= NN) return;
  float xv[HH];
#pragma unroll
  for (int j = 0; j < HH; j++) xv[j] = x[(size_t)v * HH + j];
#pragma unroll
  for (int c = 0; c < CC; c++) {
    float a = 0.f;
#pragma unroll
    for (int j = 0; j < HH; j++) a += xv[j] * W[j * CC + c];
    out[(size_t)v * CC + c] = a;
  }
}

// ---------- generic GCN conv pieces ----------
__global__ void k_deg(const int* __restrict__ src, const int* __restrict__ dst,
                      const unsigned char* __restrict__ ev, float* __restrict__ deg,
                      unsigned char* __restrict__ hasloop) {
  int e = blockIdx.x * blockDim.x + threadIdx.x;
  if (e >= EE) return;
  if (ev && !ev[e]) return;
  int d = dst[e];
  atomicAdd(&deg[d], 1.0f);
  if (src[e] == d) hasloop[d] = 1;
}

__global__ void k_dinv(const float* __restrict__ deg, const unsigned char* __restrict__ hasloop,
                       const unsigned char* __restrict__ nv, float* __restrict__ dinv,
                       unsigned char* __restrict__ addloop) {
  int v = blockIdx.x * blockDim.x + threadIdx.x;
  if (v >= NN) return;
  int nvv = nv ? (int)nv[v] : 1;
  unsigned char al = (nvv && !hasloop[v]) ? 1 : 0;
  float d = deg[v] + (float)al;
  dinv[v] = d > 0.f ? 1.0f / sqrtf(fmaxf(d, 1e-12f)) : 0.f;
  addloop[v] = al;
}

__global__ void k_gcn_agg(const int* __restrict__ src, const int* __restrict__ dst,
                          const unsigned char* __restrict__ ev, const float* __restrict__ dinv,
                          const float* __restrict__ h, float* __restrict__ out, int fd) {
  int e = blockIdx.x * blockDim.x + threadIdx.x;
  if (e >= EE) return;
  if (ev && !ev[e]) return;
  int s = src[e], d = dst[e];
  float c = dinv[s] * dinv[d];
  for (int j = 0; j < fd; j++)
    atomicAdd(&out[(size_t)d * fd + j], h[(size_t)s * fd + j] * c);
}

__global__ void k_gcn_fin(const float* __restrict__ h, const float* __restrict__ dinv,
                          const unsigned char* __restrict__ addloop, const float* __restrict__ b,
                          float* __restrict__ out, int fd, int relu) {
  int v = blockIdx.x * blockDim.x + threadIdx.x;
  if (v >= NN) return;
  float c = addloop[v] ? dinv[v] * dinv[v] : 0.f;
  for (int j = 0; j < fd; j++) {
    float o = out[(size_t)v * fd + j] + c * h[(size_t)v * fd + j] + b[j];
    if (relu) o = fmaxf(o, 0.f);
    out[(size_t)v * fd + j] = o;
  }
}

// ---------- edge pool: scores ----------
__global__ void k_raw(const float* __restrict__ x, const int* __restrict__ src,
                      const int* __restrict__ dst, const unsigned char* __restrict__ ev,
                      const float* __restrict__ Wp, const float* __restrict__ bp,
                      float* __restrict__ raw, unsigned int* __restrict__ mEnc, int fd) {
  int e = blockIdx.x * blockDim.x + threadIdx.x;
  if (e >= EE) return;
  if (ev && !ev[e]) return;
  int s = src[e], d = dst[e];
  float r = bp[0];
  for (int j = 0; j < fd; j++) r += x[(size_t)s * fd + j] * Wp[j];
  for (int j = 0; j < fd; j++) r += x[(size_t)d * fd + j] * Wp[fd + j];
  raw[e] = r;
  atomicMax(&mEnc[d], encf(r));
}

__global__ void k_exps(const float* __restrict__ raw, const int* __restrict__ dst,
                       const unsigned char* __restrict__ ev, const unsigned int* __restrict__ mEnc,
                       float* __restrict__ ex, float* __restrict__ ssum) {
  int e = blockIdx.x * blockDim.x + threadIdx.x;
  if (e >= EE) return;
  if (ev && !ev[e]) return;
  int d = dst[e];
  unsigned int me = mEnc[d];
  float m = me ? decf(me) : 0.f;
  float v = expf(raw[e] - m);
  ex[e] = v;
  atomicAdd(&ssum[d], v);
}

__global__ void k_score(const float* __restrict__ ex, const int* __restrict__ dst,
                        const unsigned char* __restrict__ ev, const float* __restrict__ ssum,
                        float* __restrict__ score) {
  int e = blockIdx.x * blockDim.x + threadIdx.x;
  if (e >= EE) return;
  if (ev && !ev[e]) return;
  float sd = ssum[dst[e]];
  score[e] = ex[e] / (sd > 0.f ? sd : 1.0f) + 0.5f;
}

// ---------- partition edges by graph into packed records ----------
// record = { prio = score_bits<<32 | ~e , payload = s<<32 | d }
__global__ void k_part(const int* __restrict__ src, const int* __restrict__ dst,
                       const float* __restrict__ score, const unsigned char* __restrict__ ev,
                       ulonglong2* __restrict__ recs, int* __restrict__ gcnts) {
  int e = blockIdx.x * blockDim.x + threadIdx.x;
  int lane = threadIdx.x & 63;
  int valid = 0, s = 0, d = 0, g = -1;
  if (e < EE && (!ev || ev[e])) {
    valid = 1;
    s = src[e];
    d = dst[e];
    g = s / GS;
  }
  unsigned long long p = 0;
  if (valid)
    p = (((unsigned long long)__float_as_uint(score[e])) << 32) |
        (unsigned int)(~(unsigned int)e);
  for (int gg = 0; gg < BB; gg++) {
    unsigned long long m = __ballot(valid && g == gg);
    if (!m) continue;
    int tot = __popcll(m);
    int leader = __ffsll((long long)m) - 1;
    int base = 0;
    if (lane == leader) base = atomicAdd(&gcnts[gg], tot);
    base = __shfl(base, leader, 64);
    if (valid && g == gg) {
      int pre = __popcll(m & ((1ULL << lane) - 1ULL));
      recs[(size_t)gg * CAP + base + pre] =
          make_ulonglong2(p, (((unsigned long long)(unsigned int)s) << 32) | (unsigned int)d);
    }
  }
}

// ---------- matching: per-graph locally-dominant greedy, all-LDS state ----------
// One block per graph. best[] + rem bitset in LDS; records ping-pong in global.
// Fixpoint == sequential greedy by (score desc, index asc): bit-exact.
__global__ __launch_bounds__(1024) void k_match_g(ulonglong2* __restrict__ recs0,
                                                  ulonglong2* __restrict__ recs1,
                                                  const int* __restrict__ gcnts,
                                                  const unsigned char* __restrict__ nv,
                                                  unsigned char* __restrict__ chosen) {
  __shared__ unsigned long long best[GS];
  __shared__ unsigned int remB[REMW];
  __shared__ int cnt_next;
  const int g = blockIdx.x;
  const int base = g * GS;
  const int t = threadIdx.x, nth = blockDim.x;
  const int lane = t & 63;

  for (int w = t; w < REMW; w += nth) {
    unsigned int bits = 0;
    for (int b = 0; b < 32; b++) {
      int v = w * 32 + b;
      if (v < GS) bits |= (nv ? (nv[base + v] ? 1u : 0u) : 1u) << b;
    }
    remB[w] = bits;
  }
  for (int i = t; i < GS; i += nth) best[i] = 0ULL;
  __syncthreads();

  ulonglong2* bufs[2] = {recs0 + (size_t)g * CAP, recs1 + (size_t)g * CAP};
  int n = gcnts[g];
  int cur = 0;

  while (n > 0) {
    // P1: live edges post priority at both endpoints (LDS atomicMax)
    for (int i = t; i < n; i += nth) {
      ulonglong2 r = bufs[cur][i];
      int ls = (int)(r.y >> 32) - base, ld = (int)(r.y & 0xFFFFFFFFu) - base;
      if (((remB[ls >> 5] >> (ls & 31)) & 1u) && ((remB[ld >> 5] >> (ld & 31)) & 1u)) {
        atomicMax(&best[ls], r.x);
        if (ld != ls) atomicMax(&best[ld], r.x);
      }
    }
    if (t == 0) cnt_next = 0;
    __syncthreads();
    // P2: local winners commit; survivors compact into other buffer
    for (int i = t; i < n; i += nth) {
      ulonglong2 r = bufs[cur][i];
      int ls = (int)(r.y >> 32) - base, ld = (int)(r.y & 0xFFFFFFFFu) - base;
      int keep = 0;
      if (((remB[ls >> 5] >> (ls & 31)) & 1u) && ((remB[ld >> 5] >> (ld & 31)) & 1u)) {
        if (best[ls] == r.x && best[ld] == r.x) {
          int e = (int)(~(unsigned int)(r.x & 0xFFFFFFFFu));
          chosen[e] = 1;
          atomicAnd(&remB[ls >> 5], ~(1u << (ls & 31)));
          atomicAnd(&remB[ld >> 5], ~(1u << (ld & 31)));
        } else {
          keep = 1;
        }
      }
      unsigned long long m = __ballot(keep);
      int tot = __popcll(m);
      int pre = __popcll(m & ((1ULL << lane) - 1ULL));
      int b0 = 0;
      if (lane == 0 && tot) b0 = atomicAdd(&cnt_next, tot);
      b0 = __shfl(b0, 0, 64);
      if (keep) bufs[cur ^ 1][b0 + pre] = r;
    }
    __syncthreads();
    n = cnt_next;
    for (int i = t; i < GS; i += nth) best[i] = 0ULL;
    __syncthreads();
    cur ^= 1;
  }
}

// ---------- edge pool: post-matching ----------
__global__ void k_pool_node(const unsigned char* __restrict__ nvin, unsigned char* __restrict__ nvout,
                            float* __restrict__ scale) {
  int v = blockIdx.x * blockDim.x + threadIdx.x;
  if (v >= NN) return;
  nvout[v] = nvin ? nvin[v] : 1;
  scale[v] = 1.0f;
}

__global__ void k_pool_edge(const int* __restrict__ src, const int* __restrict__ dst,
                            const unsigned char* __restrict__ chosen, const float* __restrict__ score,
                            const float* __restrict__ x, unsigned char* __restrict__ nvout,
                            float* __restrict__ scale, float* __restrict__ added,
                            int* __restrict__ merged, int fd) {
  int e = blockIdx.x * blockDim.x + threadIdx.x;
  if (e >= EE) return;
  if (!chosen[e]) return;
  int s = src[e], d = dst[e];
  scale[s] = score[e];
  if (merged) merged[d] = s;
  if (s != d) {
    nvout[d] = 0;
    for (int j = 0; j < fd; j++) added[(size_t)s * fd + j] = x[(size_t)d * fd + j];
  }
}

__global__ void k_newx(const float* __restrict__ x, const float* __restrict__ added,
                       const float* __restrict__ scale, const unsigned char* __restrict__ nvout,
                       float* __restrict__ newx, int fd) {
  int v = blockIdx.x * blockDim.x + threadIdx.x;
  if (v >= NN) return;
  float sc = scale[v];
  int ok = nvout[v];
  for (int j = 0; j < fd; j++)
    newx[(size_t)v * fd + j] =
        ok ? (x[(size_t)v * fd + j] + added[(size_t)v * fd + j]) * sc : 0.f;
}

__global__ void k_cmap(const int* __restrict__ merged, int* __restrict__ cmap) {
  int v = blockIdx.x * blockDim.x + threadIdx.x;
  if (v >= NN) return;
  int m = merged[v];
  cmap[v] = m >= 0 ? m : v;
}

__global__ void k_remap(const int* __restrict__ src, const int* __restrict__ dst,
                        const int* __restrict__ cmap, int* __restrict__ ns, int* __restrict__ nd) {
  int e = blockIdx.x * blockDim.x + threadIdx.x;
  if (e >= EE) return;
  ns[e] = cmap[src[e]];
  nd[e] = cmap[dst[e]];
}

// ---------- dedup via hash: keep min original index per (ns,nd) ----------
__device__ __forceinline__ unsigned int ht_hash(unsigned long long key) {
  return (unsigned int)((key * 0x9E3779B97F4A7C15ULL) >> 44) & HT_MASK;
}

__global__ void k_dedup_ins(const int* __restrict__ ns, const int* __restrict__ nd,
                            unsigned long long* __restrict__ htab) {
  int e = blockIdx.x * blockDim.x + threadIdx.x;
  if (e >= EE) return;
  unsigned long long key =
      (unsigned long long)((((unsigned int)ns[e]) << 16) | (unsigned int)nd[e]);
  unsigned long long val = (key << 32) | (unsigned int)e;
  unsigned int h = ht_hash(key);
  for (;;) {
    unsigned long long curv = htab[h];
    if (curv == ~0ULL) {
      unsigned long long prev = atomicCAS(&htab[h], ~0ULL, val);
      if (prev == ~0ULL) break;
      curv = prev;
    }
    if ((curv >> 32) == key) {
      atomicMin(&htab[h], val);
      break;
    }
    h = (h + 1) & HT_MASK;
  }
}

__global__ void k_dedup_mark(const int* __restrict__ ns, const int* __restrict__ nd,
                             const unsigned long long* __restrict__ htab,
                             unsigned char* __restrict__ evout) {
  int e = blockIdx.x * blockDim.x + threadIdx.x;
  if (e >= EE) return;
  unsigned long long key =
      (unsigned long long)((((unsigned int)ns[e]) << 16) | (unsigned int)nd[e]);
  unsigned int h = ht_hash(key);
  for (;;) {
    unsigned long long curv = htab[h];
    if ((curv >> 32) == key) {
      evout[e] = ((curv & 0xFFFFFFFFULL) == (unsigned long long)(unsigned int)e) ? 1 : 0;
      return;
    }
    h = (h + 1) & HT_MASK;
  }
}

// ---------- readout ----------
__global__ void k_graphpool(const float* __restrict__ h, const unsigned char* __restrict__ nv,
                            const int* __restrict__ batch, float* __restrict__ gsum,
                            float* __restrict__ gcnt) {
  int v = blockIdx.x * blockDim.x + threadIdx.x;
  int lane = threadIdx.x & 63;
  int vc = v < NN ? v : NN - 1;
  int b = batch[vc];
  int active = (v < NN) && nv[v];
  float cnt = active ? 1.f : 0.f;
  float val[CC];
  for (int j = 0; j < CC; j++) val[j] = active ? h[(size_t)v * CC + j] : 0.f;
  int b0 = __shfl(b, 0, 64);
  unsigned long long same = __ballot(b == b0);
  if (same == ~0ULL) {
    for (int o = 32; o > 0; o >>= 1) {
      cnt += __shfl_down(cnt, o, 64);
      for (int j = 0; j < CC; j++) val[j] += __shfl_down(val[j], o, 64);
    }
    if (lane == 0 && cnt > 0.f) {
      atomicAdd(&gcnt[b0], cnt);
      for (int j = 0; j < CC; j++) atomicAdd(&gsum[b0 * CC + j], val[j]);
    }
  } else if (active) {
    atomicAdd(&gcnt[b], cnt);
    for (int j = 0; j < CC; j++) atomicAdd(&gsum[b * CC + j], val[j]);
  }
}

__global__ void k_logsm(const float* __restrict__ gsum, const float* __restrict__ gcnt,
                        float* __restrict__ out) {
  int t = threadIdx.x;
  if (t >= BB) return;
  float gr[CC];
  float c = gcnt[t];
  float m = -INFINITY;
  for (int j = 0; j < CC; j++) {
    gr[j] = gsum[t * CC + j] / c;
    m = fmaxf(m, gr[j]);
  }
  float s = 0.f;
  for (int j = 0; j < CC; j++) s += expf(gr[j] - m);
  float l = logf(s);
  for (int j = 0; j < CC; j++) out[t * CC + j] = gr[j] - m - l;
}

// ---------- host ----------
extern "C" void kernel_launch(void* const* d_in, const int* in_sizes, int n_in,
                              void* d_out, int out_size, void* d_ws, size_t ws_size,
                              hipStream_t stream) {
  const float* x = (const float*)d_in[0];
  const int* src = (const int*)d_in[1];
  const int* dst = (const int*)d_in[2];
  const int* batch = (const int*)d_in[3];
  const float* W1 = (const float*)d_in[4];
  const float* b1 = (const float*)d_in[5];
  const float* W2 = (const float*)d_in[6];
  const float* b2 = (const float*)d_in[7];
  const float* Wp1 = (const float*)d_in[8];
  const float* bp1 = (const float*)d_in[9];
  const float* Wp2 = (const float*)d_in[10];
  const float* bp2 = (const float*)d_in[11];
  float* out = (float*)d_out;

  char* wsb = (char*)d_ws;
  size_t off = 0;
  auto A = [&](size_t bytes) -> char* {
    char* r = wsb + off;
    off = (off + bytes + 255) & ~(size_t)255;
    return r;
  };
  float* h1pre = (float*)A((size_t)NN * HH * 4);
  float* h1out = (float*)A((size_t)NN * HH * 4);
  float* deg = (float*)A((size_t)NN * 4);
  float* dinv = (float*)A((size_t)NN * 4);
  unsigned char* hasloop = (unsigned char*)A(NN);
  unsigned char* addloop = (unsigned char*)A(NN);
  float* raw = (float*)A((size_t)EE * 4);
  float* ex = (float*)A((size_t)EE * 4);
  float* score = (float*)A((size_t)EE * 4);
  unsigned int* mEnc = (unsigned int*)A((size_t)NN * 4);
  float* ssum = (float*)A((size_t)NN * 4);
  unsigned char* chosen = (unsigned char*)A(EE);
  unsigned char* nv1 = (unsigned char*)A(NN);
  unsigned char* nv2 = (unsigned char*)A(NN);
  float* scale = (float*)A((size_t)NN * 4);
  float* added = (float*)A((size_t)NN * CC * 4);
  float* newx1 = (float*)A((size_t)NN * HH * 4);
  int* merged = (int*)A((size_t)NN * 4);
  int* cmap = (int*)A((size_t)NN * 4);
  int* ns = (int*)A((size_t)EE * 4);
  int* nd = (int*)A((size_t)EE * 4);
  unsigned char* ev1 = (unsigned char*)A(EE);
  unsigned long long* htab = (unsigned long long*)A((size_t)HT_SIZE * 8);
  float* h2pre = (float*)A((size_t)NN * CC * 4);
  float* h2out = (float*)A((size_t)NN * CC * 4);
  float* newx2 = (float*)A((size_t)NN * CC * 4);
  ulonglong2* recs0 = (ulonglong2*)A((size_t)BB * CAP * 16);
  ulonglong2* recs1 = (ulonglong2*)A((size_t)BB * CAP * 16);
  int* gcnts = (int*)A(64);
  float* gsum = (float*)A((size_t)BB * CC * 4);
  float* gcnt = (float*)A((size_t)BB * 4);
  (void)ws_size; (void)n_in; (void)in_sizes; (void)out_size;

  const int GE = ngrid(EE), GN = ngrid(NN);

  // ===== stage 1: GCNConv(384->6) + ReLU =====
  hipLaunchKernelGGL(k_mm1, dim3((NN + 3) / 4), dim3(TPB), 0, stream, x, W1, h1pre);
  hipMemsetAsync(deg, 0, (size_t)NN * 4, stream);
  hipMemsetAsync(hasloop, 0, NN, stream);
  hipMemsetAsync(h1out, 0, (size_t)NN * HH * 4, stream);
  hipLaunchKernelGGL(k_deg, dim3(GE), dim3(TPB), 0, stream, src, dst, (const unsigned char*)nullptr, deg, hasloop);
  hipLaunchKernelGGL(k_dinv, dim3(GN), dim3(TPB), 0, stream, deg, hasloop, (const unsigned char*)nullptr, dinv, addloop);
  hipLaunchKernelGGL(k_gcn_agg, dim3(GE), dim3(TPB), 0, stream, src, dst, (const unsigned char*)nullptr, dinv, h1pre, h1out, HH);
  hipLaunchKernelGGL(k_gcn_fin, dim3(GN), dim3(TPB), 0, stream, h1pre, dinv, addloop, b1, h1out, HH, 1);

  // ===== edge pool 1 =====
  hipMemsetAsync(mEnc, 0, (size_t)NN * 4, stream);
  hipMemsetAsync(ssum, 0, (size_t)NN * 4, stream);
  hipLaunchKernelGGL(k_raw, dim3(GE), dim3(TPB), 0, stream, h1out, src, dst, (const unsigned char*)nullptr, Wp1, bp1, raw, mEnc, HH);
  hipLaunchKernelGGL(k_exps, dim3(GE), dim3(TPB), 0, stream, raw, dst, (const unsigned char*)nullptr, mEnc, ex, ssum);
  hipLaunchKernelGGL(k_score, dim3(GE), dim3(TPB), 0, stream, ex, dst, (const unsigned char*)nullptr, ssum, score);
  hipMemsetAsync(chosen, 0, EE, stream);
  hipMemsetAsync(gcnts, 0, 64, stream);
  hipLaunchKernelGGL(k_part, dim3(GE), dim3(TPB), 0, stream, src, dst, score, (const unsigned char*)nullptr, recs0, gcnts);
  hipLaunchKernelGGL(k_match_g, dim3(BB), dim3(1024), 0, stream, recs0, recs1, gcnts, (const unsigned char*)nullptr, chosen);
  hipMemsetAsync(added, 0, (size_t)NN * CC * 4, stream);
  hipMemsetAsync(merged, 0xFF, (size_t)NN * 4, stream);
  hipLaunchKernelGGL(k_pool_node, dim3(GN), dim3(TPB), 0, stream, (const unsigned char*)nullptr, nv1, scale);
  hipLaunchKernelGGL(k_pool_edge, dim3(GE), dim3(TPB), 0, stream, src, dst, chosen, score, h1out, nv1, scale, added, merged, HH);
  hipLaunchKernelGGL(k_newx, dim3(GN), dim3(TPB), 0, stream, h1out, added, scale, nv1, newx1, HH);
  hipLaunchKernelGGL(k_cmap, dim3(GN), dim3(TPB), 0, stream, merged, cmap);
  hipLaunchKernelGGL(k_remap, dim3(GE), dim3(TPB), 0, stream, src, dst, cmap, ns, nd);
  hipMemsetAsync(htab, 0xFF, (size_t)HT_SIZE * 8, stream);
  hipLaunchKernelGGL(k_dedup_ins, dim3(GE), dim3(TPB), 0, stream, ns, nd, htab);
  hipLaunchKernelGGL(k_dedup_mark, dim3(GE), dim3(TPB), 0, stream, ns, nd, htab, ev1);

  // ===== stage 2: GCNConv(6->10) =====
  hipLaunchKernelGGL(k_mm2, dim3(GN), dim3(TPB), 0, stream, newx1, W2, h2pre);
  hipMemsetAsync(deg, 0, (size_t)NN * 4, stream);
  hipMemsetAsync(hasloop, 0, NN, stream);
  hipMemsetAsync(h2out, 0, (size_t)NN * CC * 4, stream);
  hipLaunchKernelGGL(k_deg, dim3(GE), dim3(TPB), 0, stream, ns, nd, (const unsigned char*)ev1, deg, hasloop);
  hipLaunchKernelGGL(k_dinv, dim3(GN), dim3(TPB), 0, stream, deg, hasloop, (const unsigned char*)nv1, dinv, addloop);
  hipLaunchKernelGGL(k_gcn_agg, dim3(GE), dim3(TPB), 0, stream, ns, nd, (const unsigned char*)ev1, dinv, h2pre, h2out, CC);
  hipLaunchKernelGGL(k_gcn_fin, dim3(GN), dim3(TPB), 0, stream, h2pre, dinv, addloop, b2, h2out, CC, 0);

  // ===== edge pool 2 =====
  hipMemsetAsync(mEnc, 0, (size_t)NN * 4, stream);
  hipMemsetAsync(ssum, 0, (size_t)NN * 4, stream);
  hipLaunchKernelGGL(k_raw, dim3(GE), dim3(TPB), 0, stream, h2out, ns, nd, (const unsigned char*)ev1, Wp2, bp2, raw, mEnc, CC);
  hipLaunchKernelGGL(k_exps, dim3(GE), dim3(TPB), 0, stream, raw, nd, (const unsigned char*)ev1, mEnc, ex, ssum);
  hipLaunchKernelGGL(k_score, dim3(GE), dim3(TPB), 0, stream, ex, nd, (const unsigned char*)ev1, ssum, score);
  hipMemsetAsync(chosen, 0, EE, stream);
  hipMemsetAsync(gcnts, 0, 64, stream);
  hipLaunchKernelGGL(k_part, dim3(GE), dim3(TPB), 0, stream, ns, nd, score, (const unsigned char*)ev1, recs0, gcnts);
  hipLaunchKernelGGL(k_match_g, dim3(BB), dim3(1024), 0, stream, recs0, recs1, gcnts, (const unsigned char*)nv1, chosen);
  hipMemsetAsync(added, 0, (size_t)NN * CC * 4, stream);
  hipLaunchKernelGGL(k_pool_node, dim3(GN), dim3(TPB), 0, stream, (const unsigned char*)nv1, nv2, scale);
  hipLaunchKernelGGL(k_pool_edge, dim3(GE), dim3(TPB), 0, stream, ns, nd, chosen, score, h2out, nv2, scale, added, (int*)nullptr, CC);
  hipLaunchKernelGGL(k_newx, dim3(GN), dim3(TPB), 0, stream, h2out, added, scale, nv2, newx2, CC);

  // ===== readout =====
  hipMemsetAsync(gsum, 0, (size_t)BB * CC * 4, stream);
  hipMemsetAsync(gcnt, 0, (size_t)BB * 4, stream);
  hipLaunchKernelGGL(k_graphpool, dim3(GN), dim3(TPB), 0, stream, newx2, nv2, batch, gsum, gcnt);
  hipLaunchKernelGGL(k_logsm, dim3(1), dim3(64), 0, stream, gsum, gcnt, out);
}

// Round 4
// 2054.917 us; speedup vs baseline: 4.5896x; 1.7682x over previous
//
#include <hip/hip_runtime.h>
#include <math.h>

#define NN 60000
#define BB 8
#define GS 7500   // nodes per graph
#define FF 384
#define EE 600000
#define HH 6
#define CC 10
#define HT_BITS 20
#define HT_SIZE (1u << HT_BITS)
#define HT_MASK (HT_SIZE - 1u)
#define TPB 256
#define CAP 80000  // per-graph edge capacity (mean 75000, sigma ~256)
#define REMW ((GS + 31) / 32)
#define GPAD 32    // gcnts padding: one counter per 128B

static inline int ngrid(int n) { return (n + TPB - 1) / TPB; }

// ---------- helpers ----------
__device__ __forceinline__ unsigned int encf(float v) {
  unsigned int b = __float_as_uint(v);
  return (b & 0x80000000u) ? ~b : (b | 0x80000000u);
}
__device__ __forceinline__ float decf(unsigned int u) {
  unsigned int b = (u & 0x80000000u) ? (u & 0x7FFFFFFFu) : ~u;
  return __uint_as_float(b);
}

// ---------- stage 1 matmul: h1pre = x @ W1 (N x 384 @ 384 x 6) ----------
__global__ void k_mm1(const float* __restrict__ x, const float* __restrict__ W,
                      float* __restrict__ out) {
  __shared__ float Ws[FF * HH];
  for (int i = threadIdx.x; i < FF * HH; i += blockDim.x) Ws[i] = W[i];
  __syncthreads();
  int wave = threadIdx.x >> 6, lane = threadIdx.x & 63;
  int node = blockIdx.x * 4 + wave;
  if (node >= NN) return;
  const float* xr = x + (size_t)node * FF;
  float acc[HH] = {0.f, 0.f, 0.f, 0.f, 0.f, 0.f};
  for (int k = lane; k < FF; k += 64) {
    float xv = xr[k];
#pragma unroll
    for (int j = 0; j < HH; j++) acc[j] += xv * Ws[k * HH + j];
  }
#pragma unroll
  for (int j = 0; j < HH; j++) {
#pragma unroll
    for (int o = 32; o > 0; o >>= 1) acc[j] += __shfl_down(acc[j], o, 64);
  }
  if (lane == 0) {
#pragma unroll
    for (int j = 0; j < HH; j++) out[(size_t)node * HH + j] = acc[j];
  }
}

// ---------- stage 2 matmul ----------
__global__ void k_mm2(const float* __restrict__ x, const float* __restrict__ W,
                      float* __restrict__ out) {
  int v = blockIdx.x * blockDim.x + threadIdx.x;
  if (v >= NN) return;
  float xv[HH];
#pragma unroll
  for (int j = 0; j < HH; j++) xv[j] = x[(size_t)v * HH + j];
#pragma unroll
  for (int c = 0; c < CC; c++) {
    float a = 0.f;
#pragma unroll
    for (int j = 0; j < HH; j++) a += xv[j] * W[j * CC + c];
    out[(size_t)v * CC + c] = a;
  }
}

// ---------- fused per-stage zeroing (replaces ~6 memsets) ----------
__global__ void k_prep(float* __restrict__ deg, unsigned char* __restrict__ hasloop,
                       unsigned int* __restrict__ mEnc, float* __restrict__ ssum,
                       float* __restrict__ hout, int fd, int* __restrict__ gcnts,
                       float* __restrict__ gsum, float* __restrict__ gcnt) {
  int v = blockIdx.x * blockDim.x + threadIdx.x;
  if (v >= NN) return;
  deg[v] = 0.f;
  hasloop[v] = 0;
  mEnc[v] = 0;
  ssum[v] = 0.f;
  for (int j = 0; j < fd; j++) hout[(size_t)v * fd + j] = 0.f;
  if (v < BB * GPAD) gcnts[v] = 0;
  if (v < BB * CC) gsum[v] = 0.f;
  if (v < BB) gcnt[v] = 0.f;
}

// ---------- generic GCN conv pieces ----------
__global__ void k_deg(const int* __restrict__ src, const int* __restrict__ dst,
                      const unsigned char* __restrict__ ev, float* __restrict__ deg,
                      unsigned char* __restrict__ hasloop) {
  int e = blockIdx.x * blockDim.x + threadIdx.x;
  if (e >= EE) return;
  if (ev && !ev[e]) return;
  int d = dst[e];
  atomicAdd(&deg[d], 1.0f);
  if (src[e] == d) hasloop[d] = 1;
}

__global__ void k_dinv(const float* __restrict__ deg, const unsigned char* __restrict__ hasloop,
                       const unsigned char* __restrict__ nv, float* __restrict__ dinv,
                       unsigned char* __restrict__ addloop) {
  int v = blockIdx.x * blockDim.x + threadIdx.x;
  if (v >= NN) return;
  int nvv = nv ? (int)nv[v] : 1;
  unsigned char al = (nvv && !hasloop[v]) ? 1 : 0;
  float d = deg[v] + (float)al;
  dinv[v] = d > 0.f ? 1.0f / sqrtf(fmaxf(d, 1e-12f)) : 0.f;
  addloop[v] = al;
}

__global__ void k_gcn_agg(const int* __restrict__ src, const int* __restrict__ dst,
                          const unsigned char* __restrict__ ev, const float* __restrict__ dinv,
                          const float* __restrict__ h, float* __restrict__ out, int fd) {
  int e = blockIdx.x * blockDim.x + threadIdx.x;
  if (e >= EE) return;
  if (ev && !ev[e]) return;
  int s = src[e], d = dst[e];
  float c = dinv[s] * dinv[d];
  for (int j = 0; j < fd; j++)
    atomicAdd(&out[(size_t)d * fd + j], h[(size_t)s * fd + j] * c);
}

__global__ void k_gcn_fin(const float* __restrict__ h, const float* __restrict__ dinv,
                          const unsigned char* __restrict__ addloop, const float* __restrict__ b,
                          float* __restrict__ out, int fd, int relu) {
  int v = blockIdx.x * blockDim.x + threadIdx.x;
  if (v >= NN) return;
  float c = addloop[v] ? dinv[v] * dinv[v] : 0.f;
  for (int j = 0; j < fd; j++) {
    float o = out[(size_t)v * fd + j] + c * h[(size_t)v * fd + j] + b[j];
    if (relu) o = fmaxf(o, 0.f);
    out[(size_t)v * fd + j] = o;
  }
}

// ---------- edge pool: scores ----------
__global__ void k_raw(const float* __restrict__ x, const int* __restrict__ src,
                      const int* __restrict__ dst, const unsigned char* __restrict__ ev,
                      const float* __restrict__ Wp, const float* __restrict__ bp,
                      float* __restrict__ raw, unsigned int* __restrict__ mEnc, int fd) {
  int e = blockIdx.x * blockDim.x + threadIdx.x;
  if (e >= EE) return;
  if (ev && !ev[e]) return;
  int s = src[e], d = dst[e];
  float r = bp[0];
  for (int j = 0; j < fd; j++) r += x[(size_t)s * fd + j] * Wp[j];
  for (int j = 0; j < fd; j++) r += x[(size_t)d * fd + j] * Wp[fd + j];
  raw[e] = r;
  atomicMax(&mEnc[d], encf(r));
}

__global__ void k_exps(const float* __restrict__ raw, const int* __restrict__ dst,
                       const unsigned char* __restrict__ ev, const unsigned int* __restrict__ mEnc,
                       float* __restrict__ ex, float* __restrict__ ssum) {
  int e = blockIdx.x * blockDim.x + threadIdx.x;
  if (e >= EE) return;
  if (ev && !ev[e]) return;
  int d = dst[e];
  unsigned int me = mEnc[d];
  float m = me ? decf(me) : 0.f;
  float v = expf(raw[e] - m);
  ex[e] = v;
  atomicAdd(&ssum[d], v);
}

__global__ void k_score(const float* __restrict__ ex, const int* __restrict__ dst,
                        const unsigned char* __restrict__ ev, const float* __restrict__ ssum,
                        float* __restrict__ score) {
  int e = blockIdx.x * blockDim.x + threadIdx.x;
  if (e >= EE) return;
  if (ev && !ev[e]) return;
  float sd = ssum[dst[e]];
  score[e] = ex[e] / (sd > 0.f ? sd : 1.0f) + 0.5f;
}

// ---------- partition edges by graph; block-aggregated offsets ----------
// record = { prio = score_bits<<32 | ~e , payload = s<<32 | d }
// gcnts padded: counter for graph g at gcnts[g*GPAD] (128B apart).
// Also zeroes chosen[] (covers every e).
__global__ void k_part(const int* __restrict__ src, const int* __restrict__ dst,
                       const float* __restrict__ score, const unsigned char* __restrict__ ev,
                       ulonglong2* __restrict__ recs, int* __restrict__ gcnts,
                       unsigned char* __restrict__ chosen) {
  __shared__ int wcnt[TPB / 64][BB];
  __shared__ int bbase[BB];
  int e = blockIdx.x * blockDim.x + threadIdx.x;
  int w = threadIdx.x >> 6, lane = threadIdx.x & 63;
  int valid = 0, s = 0, d = 0, g = 0;
  if (e < EE) {
    chosen[e] = 0;
    if (!ev || ev[e]) { valid = 1; s = src[e]; d = dst[e]; g = s / GS; }
  }
  unsigned long long p = 0;
  if (valid)
    p = (((unsigned long long)__float_as_uint(score[e])) << 32) |
        (unsigned int)(~(unsigned int)e);
  int myrank = 0;
#pragma unroll
  for (int gg = 0; gg < BB; gg++) {
    unsigned long long m = __ballot(valid && g == gg);
    if (valid && g == gg) myrank = __popcll(m & ((1ULL << lane) - 1ULL));
    if (lane == 0) wcnt[w][gg] = __popcll(m);
  }
  __syncthreads();
  if (threadIdx.x < BB) {
    int gg = threadIdx.x, tot = 0;
#pragma unroll
    for (int ww = 0; ww < TPB / 64; ww++) {
      int c = wcnt[ww][gg];
      wcnt[ww][gg] = tot;
      tot += c;
    }
    bbase[gg] = tot ? atomicAdd(&gcnts[gg * GPAD], tot) : 0;
  }
  __syncthreads();
  if (valid)
    recs[(size_t)g * CAP + bbase[g] + wcnt[w][g] + myrank] =
        make_ulonglong2(p, (((unsigned long long)(unsigned int)s) << 32) | (unsigned int)d);
}

// ---------- matching: per-graph locally-dominant greedy, all-LDS state ----------
// One block per graph; survivor-driven best[] clearing (O(n) per round).
__global__ __launch_bounds__(1024) void k_match_g(ulonglong2* __restrict__ recs0,
                                                  ulonglong2* __restrict__ recs1,
                                                  const int* __restrict__ gcnts,
                                                  const unsigned char* __restrict__ nv,
                                                  unsigned char* __restrict__ chosen) {
  __shared__ unsigned long long best[GS];
  __shared__ unsigned int remB[REMW];
  __shared__ int cnt_next;
  const int g = blockIdx.x;
  const int base = g * GS;
  const int t = threadIdx.x, nth = blockDim.x;
  const int lane = t & 63;

  for (int w = t; w < REMW; w += nth) {
    unsigned int bits = 0;
    for (int b = 0; b < 32; b++) {
      int v = w * 32 + b;
      if (v < GS) bits |= (nv ? (nv[base + v] ? 1u : 0u) : 1u) << b;
    }
    remB[w] = bits;
  }
  for (int i = t; i < GS; i += nth) best[i] = 0ULL;
  __syncthreads();

  ulonglong2* bufs[2] = {recs0 + (size_t)g * CAP, recs1 + (size_t)g * CAP};
  int n = gcnts[g * GPAD];
  int cur = 0;

  while (n > 0) {
    // P1: live edges post priority at both endpoints (LDS atomicMax)
    for (int i = t; i < n; i += nth) {
      ulonglong2 r = bufs[cur][i];
      int ls = (int)(r.y >> 32) - base, ld = (int)(r.y & 0xFFFFFFFFu) - base;
      if (((remB[ls >> 5] >> (ls & 31)) & 1u) && ((remB[ld >> 5] >> (ld & 31)) & 1u)) {
        atomicMax(&best[ls], r.x);
        if (ld != ls) atomicMax(&best[ld], r.x);
      }
    }
    if (t == 0) cnt_next = 0;
    __syncthreads();
    // P2: local winners commit; survivors compact into other buffer
    for (int i = t; i < n; i += nth) {
      ulonglong2 r = bufs[cur][i];
      int ls = (int)(r.y >> 32) - base, ld = (int)(r.y & 0xFFFFFFFFu) - base;
      int keep = 0;
      if (((remB[ls >> 5] >> (ls & 31)) & 1u) && ((remB[ld >> 5] >> (ld & 31)) & 1u)) {
        if (best[ls] == r.x && best[ld] == r.x) {
          int e = (int)(~(unsigned int)(r.x & 0xFFFFFFFFu));
          chosen[e] = 1;
          atomicAnd(&remB[ls >> 5], ~(1u << (ls & 31)));
          atomicAnd(&remB[ld >> 5], ~(1u << (ld & 31)));
        } else {
          keep = 1;
        }
      }
      unsigned long long m = __ballot(keep);
      int tot = __popcll(m);
      int pre = __popcll(m & ((1ULL << lane) - 1ULL));
      int b0 = 0;
      if (lane == 0 && tot) b0 = atomicAdd(&cnt_next, tot);
      b0 = __shfl(b0, 0, 64);
      if (keep) bufs[cur ^ 1][b0 + pre] = r;
    }
    __syncthreads();
    n = cnt_next;
    // P3: clear best[] only at surviving edges' endpoints (benign write races)
    for (int i = t; i < n; i += nth) {
      ulonglong2 r = bufs[cur ^ 1][i];
      int ls = (int)(r.y >> 32) - base, ld = (int)(r.y & 0xFFFFFFFFu) - base;
      best[ls] = 0ULL;
      best[ld] = 0ULL;
    }
    __syncthreads();
    cur ^= 1;
  }
}

// ---------- edge pool: post-matching ----------
// Fused init: nvout/scale/merged/added (replaces 2 memsets)
__global__ void k_pool_node(const unsigned char* __restrict__ nvin, unsigned char* __restrict__ nvout,
                            float* __restrict__ scale, int* __restrict__ merged,
                            float* __restrict__ added, int fd) {
  int v = blockIdx.x * blockDim.x + threadIdx.x;
  if (v >= NN) return;
  nvout[v] = nvin ? nvin[v] : 1;
  scale[v] = 1.0f;
  if (merged) merged[v] = -1;
  for (int j = 0; j < fd; j++) added[(size_t)v * fd + j] = 0.f;
}

__global__ void k_pool_edge(const int* __restrict__ src, const int* __restrict__ dst,
                            const unsigned char* __restrict__ chosen, const float* __restrict__ score,
                            const float* __restrict__ x, unsigned char* __restrict__ nvout,
                            float* __restrict__ scale, float* __restrict__ added,
                            int* __restrict__ merged, int fd) {
  int e = blockIdx.x * blockDim.x + threadIdx.x;
  if (e >= EE) return;
  if (!chosen[e]) return;
  int s = src[e], d = dst[e];
  scale[s] = score[e];
  if (merged) merged[d] = s;
  if (s != d) {
    nvout[d] = 0;
    for (int j = 0; j < fd; j++) added[(size_t)s * fd + j] = x[(size_t)d * fd + j];
  }
}

__global__ void k_newx(const float* __restrict__ x, const float* __restrict__ added,
                       const float* __restrict__ scale, const unsigned char* __restrict__ nvout,
                       float* __restrict__ newx, int fd) {
  int v = blockIdx.x * blockDim.x + threadIdx.x;
  if (v >= NN) return;
  float sc = scale[v];
  int ok = nvout[v];
  for (int j = 0; j < fd; j++)
    newx[(size_t)v * fd + j] =
        ok ? (x[(size_t)v * fd + j] + added[(size_t)v * fd + j]) * sc : 0.f;
}

__global__ void k_cmap(const int* __restrict__ merged, int* __restrict__ cmap) {
  int v = blockIdx.x * blockDim.x + threadIdx.x;
  if (v >= NN) return;
  int m = merged[v];
  cmap[v] = m >= 0 ? m : v;
}

__global__ void k_remap(const int* __restrict__ src, const int* __restrict__ dst,
                        const int* __restrict__ cmap, int* __restrict__ ns, int* __restrict__ nd) {
  int e = blockIdx.x * blockDim.x + threadIdx.x;
  if (e >= EE) return;
  ns[e] = cmap[src[e]];
  nd[e] = cmap[dst[e]];
}

// ---------- dedup via hash: keep min original index per (ns,nd) ----------
__device__ __forceinline__ unsigned int ht_hash(unsigned long long key) {
  return (unsigned int)((key * 0x9E3779B97F4A7C15ULL) >> 44) & HT_MASK;
}

__global__ void k_dedup_ins(const int* __restrict__ ns, const int* __restrict__ nd,
                            unsigned long long* __restrict__ htab) {
  int e = blockIdx.x * blockDim.x + threadIdx.x;
  if (e >= EE) return;
  unsigned long long key =
      (unsigned long long)((((unsigned int)ns[e]) << 16) | (unsigned int)nd[e]);
  unsigned long long val = (key << 32) | (unsigned int)e;
  unsigned int h = ht_hash(key);
  for (;;) {
    unsigned long long curv = htab[h];
    if (curv == ~0ULL) {
      unsigned long long prev = atomicCAS(&htab[h], ~0ULL, val);
      if (prev == ~0ULL) break;
      curv = prev;
    }
    if ((curv >> 32) == key) {
      atomicMin(&htab[h], val);
      break;
    }
    h = (h + 1) & HT_MASK;
  }
}

__global__ void k_dedup_mark(const int* __restrict__ ns, const int* __restrict__ nd,
                             const unsigned long long* __restrict__ htab,
                             unsigned char* __restrict__ evout) {
  int e = blockIdx.x * blockDim.x + threadIdx.x;
  if (e >= EE) return;
  unsigned long long key =
      (unsigned long long)((((unsigned int)ns[e]) << 16) | (unsigned int)nd[e]);
  unsigned int h = ht_hash(key);
  for (;;) {
    unsigned long long curv = htab[h];
    if ((curv >> 32) == key) {
      evout[e] = ((curv & 0xFFFFFFFFULL) == (unsigned long long)(unsigned int)e) ? 1 : 0;
      return;
    }
    h = (h + 1) & HT_MASK;
  }
}

// ---------- readout ----------
__global__ void k_graphpool(const float* __restrict__ h, const unsigned char* __restrict__ nv,
                            const int* __restrict__ batch, float* __restrict__ gsum,
                            float* __restrict__ gcnt) {
  int v = blockIdx.x * blockDim.x + threadIdx.x;
  int lane = threadIdx.x & 63;
  int vc = v < NN ? v : NN - 1;
  int b = batch[vc];
  int active = (v < NN) && nv[v];
  float cnt = active ? 1.f : 0.f;
  float val[CC];
  for (int j = 0; j < CC; j++) val[j] = active ? h[(size_t)v * CC + j] : 0.f;
  int b0 = __shfl(b, 0, 64);
  unsigned long long same = __ballot(b == b0);
  if (same == ~0ULL) {
    for (int o = 32; o > 0; o >>= 1) {
      cnt += __shfl_down(cnt, o, 64);
      for (int j = 0; j < CC; j++) val[j] += __shfl_down(val[j], o, 64);
    }
    if (lane == 0 && cnt > 0.f) {
      atomicAdd(&gcnt[b0], cnt);
      for (int j = 0; j < CC; j++) atomicAdd(&gsum[b0 * CC + j], val[j]);
    }
  } else if (active) {
    atomicAdd(&gcnt[b], cnt);
    for (int j = 0; j < CC; j++) atomicAdd(&gsum[b * CC + j], val[j]);
  }
}

__global__ void k_logsm(const float* __restrict__ gsum, const float* __restrict__ gcnt,
                        float* __restrict__ out) {
  int t = threadIdx.x;
  if (t >= BB) return;
  float gr[CC];
  float c = gcnt[t];
  float m = -INFINITY;
  for (int j = 0; j < CC; j++) {
    gr[j] = gsum[t * CC + j] / c;
    m = fmaxf(m, gr[j]);
  }
  float s = 0.f;
  for (int j = 0; j < CC; j++) s += expf(gr[j] - m);
  float l = logf(s);
  for (int j = 0; j < CC; j++) out[t * CC + j] = gr[j] - m - l;
}

// ---------- host ----------
extern "C" void kernel_launch(void* const* d_in, const int* in_sizes, int n_in,
                              void* d_out, int out_size, void* d_ws, size_t ws_size,
                              hipStream_t stream) {
  const float* x = (const float*)d_in[0];
  const int* src = (const int*)d_in[1];
  const int* dst = (const int*)d_in[2];
  const int* batch = (const int*)d_in[3];
  const float* W1 = (const float*)d_in[4];
  const float* b1 = (const float*)d_in[5];
  const float* W2 = (const float*)d_in[6];
  const float* b2 = (const float*)d_in[7];
  const float* Wp1 = (const float*)d_in[8];
  const float* bp1 = (const float*)d_in[9];
  const float* Wp2 = (const float*)d_in[10];
  const float* bp2 = (const float*)d_in[11];
  float* out = (float*)d_out;

  char* wsb = (char*)d_ws;
  size_t off = 0;
  auto A = [&](size_t bytes) -> char* {
    char* r = wsb + off;
    off = (off + bytes + 255) & ~(size_t)255;
    return r;
  };
  float* h1pre = (float*)A((size_t)NN * HH * 4);
  float* h1out = (float*)A((size_t)NN * HH * 4);
  float* deg = (float*)A((size_t)NN * 4);
  float* dinv = (float*)A((size_t)NN * 4);
  unsigned char* hasloop = (unsigned char*)A(NN);
  unsigned char* addloop = (unsigned char*)A(NN);
  float* raw = (float*)A((size_t)EE * 4);
  float* ex = (float*)A((size_t)EE * 4);
  float* score = (float*)A((size_t)EE * 4);
  unsigned int* mEnc = (unsigned int*)A((size_t)NN * 4);
  float* ssum = (float*)A((size_t)NN * 4);
  unsigned char* chosen = (unsigned char*)A(EE);
  unsigned char* nv1 = (unsigned char*)A(NN);
  unsigned char* nv2 = (unsigned char*)A(NN);
  float* scale = (float*)A((size_t)NN * 4);
  float* added = (float*)A((size_t)NN * CC * 4);
  float* newx1 = (float*)A((size_t)NN * HH * 4);
  int* merged = (int*)A((size_t)NN * 4);
  int* cmap = (int*)A((size_t)NN * 4);
  int* ns = (int*)A((size_t)EE * 4);
  int* nd = (int*)A((size_t)EE * 4);
  unsigned char* ev1 = (unsigned char*)A(EE);
  unsigned long long* htab = (unsigned long long*)A((size_t)HT_SIZE * 8);
  float* h2pre = (float*)A((size_t)NN * CC * 4);
  float* h2out = (float*)A((size_t)NN * CC * 4);
  float* newx2 = (float*)A((size_t)NN * CC * 4);
  ulonglong2* recs0 = (ulonglong2*)A((size_t)BB * CAP * 16);
  ulonglong2* recs1 = (ulonglong2*)A((size_t)BB * CAP * 16);
  int* gcnts = (int*)A((size_t)BB * GPAD * 4);
  float* gsum = (float*)A((size_t)BB * CC * 4);
  float* gcnt = (float*)A((size_t)BB * 4);
  (void)ws_size; (void)n_in; (void)in_sizes; (void)out_size;

  const int GE = ngrid(EE), GN = ngrid(NN);

  // ===== stage 1: GCNConv(384->6) + ReLU =====
  hipLaunchKernelGGL(k_mm1, dim3((NN + 3) / 4), dim3(TPB), 0, stream, x, W1, h1pre);
  hipLaunchKernelGGL(k_prep, dim3(GN), dim3(TPB), 0, stream, deg, hasloop, mEnc, ssum, h1out, HH, gcnts, gsum, gcnt);
  hipLaunchKernelGGL(k_deg, dim3(GE), dim3(TPB), 0, stream, src, dst, (const unsigned char*)nullptr, deg, hasloop);
  hipLaunchKernelGGL(k_dinv, dim3(GN), dim3(TPB), 0, stream, deg, hasloop, (const unsigned char*)nullptr, dinv, addloop);
  hipLaunchKernelGGL(k_gcn_agg, dim3(GE), dim3(TPB), 0, stream, src, dst, (const unsigned char*)nullptr, dinv, h1pre, h1out, HH);
  hipLaunchKernelGGL(k_gcn_fin, dim3(GN), dim3(TPB), 0, stream, h1pre, dinv, addloop, b1, h1out, HH, 1);

  // ===== edge pool 1 =====
  hipLaunchKernelGGL(k_raw, dim3(GE), dim3(TPB), 0, stream, h1out, src, dst, (const unsigned char*)nullptr, Wp1, bp1, raw, mEnc, HH);
  hipLaunchKernelGGL(k_exps, dim3(GE), dim3(TPB), 0, stream, raw, dst, (const unsigned char*)nullptr, mEnc, ex, ssum);
  hipLaunchKernelGGL(k_score, dim3(GE), dim3(TPB), 0, stream, ex, dst, (const unsigned char*)nullptr, ssum, score);
  hipLaunchKernelGGL(k_part, dim3(GE), dim3(TPB), 0, stream, src, dst, score, (const unsigned char*)nullptr, recs0, gcnts, chosen);
  hipLaunchKernelGGL(k_match_g, dim3(BB), dim3(1024), 0, stream, recs0, recs1, gcnts, (const unsigned char*)nullptr, chosen);
  hipLaunchKernelGGL(k_pool_node, dim3(GN), dim3(TPB), 0, stream, (const unsigned char*)nullptr, nv1, scale, merged, added, HH);
  hipLaunchKernelGGL(k_pool_edge, dim3(GE), dim3(TPB), 0, stream, src, dst, chosen, score, h1out, nv1, scale, added, merged, HH);
  hipLaunchKernelGGL(k_newx, dim3(GN), dim3(TPB), 0, stream, h1out, added, scale, nv1, newx1, HH);
  hipLaunchKernelGGL(k_cmap, dim3(GN), dim3(TPB), 0, stream, merged, cmap);
  hipLaunchKernelGGL(k_remap, dim3(GE), dim3(TPB), 0, stream, src, dst, cmap, ns, nd);
  hipMemsetAsync(htab, 0xFF, (size_t)HT_SIZE * 8, stream);
  hipLaunchKernelGGL(k_dedup_ins, dim3(GE), dim3(TPB), 0, stream, ns, nd, htab);
  hipLaunchKernelGGL(k_dedup_mark, dim3(GE), dim3(TPB), 0, stream, ns, nd, htab, ev1);

  // ===== stage 2: GCNConv(6->10) =====
  hipLaunchKernelGGL(k_mm2, dim3(GN), dim3(TPB), 0, stream, newx1, W2, h2pre);
  hipLaunchKernelGGL(k_prep, dim3(GN), dim3(TPB), 0, stream, deg, hasloop, mEnc, ssum, h2out, CC, gcnts, gsum, gcnt);
  hipLaunchKernelGGL(k_deg, dim3(GE), dim3(TPB), 0, stream, ns, nd, (const unsigned char*)ev1, deg, hasloop);
  hipLaunchKernelGGL(k_dinv, dim3(GN), dim3(TPB), 0, stream, deg, hasloop, (const unsigned char*)nv1, dinv, addloop);
  hipLaunchKernelGGL(k_gcn_agg, dim3(GE), dim3(TPB), 0, stream, ns, nd, (const unsigned char*)ev1, dinv, h2pre, h2out, CC);
  hipLaunchKernelGGL(k_gcn_fin, dim3(GN), dim3(TPB), 0, stream, h2pre, dinv, addloop, b2, h2out, CC, 0);

  // ===== edge pool 2 =====
  hipLaunchKernelGGL(k_raw, dim3(GE), dim3(TPB), 0, stream, h2out, ns, nd, (const unsigned char*)ev1, Wp2, bp2, raw, mEnc, CC);
  hipLaunchKernelGGL(k_exps, dim3(GE), dim3(TPB), 0, stream, raw, nd, (const unsigned char*)ev1, mEnc, ex, ssum);
  hipLaunchKernelGGL(k_score, dim3(GE), dim3(TPB), 0, stream, ex, nd, (const unsigned char*)ev1, ssum, score);
  hipLaunchKernelGGL(k_part, dim3(GE), dim3(TPB), 0, stream, ns, nd, score, (const unsigned char*)ev1, recs0, gcnts, chosen);
  hipLaunchKernelGGL(k_match_g, dim3(BB), dim3(1024), 0, stream, recs0, recs1, gcnts, (const unsigned char*)nv1, chosen);
  hipLaunchKernelGGL(k_pool_node, dim3(GN), dim3(TPB), 0, stream, (const unsigned char*)nv1, nv2, scale, (int*)nullptr, added, CC);
  hipLaunchKernelGGL(k_pool_edge, dim3(GE), dim3(TPB), 0, stream, ns, nd, chosen, score, h2out, nv2, scale, added, (int*)nullptr, CC);
  hipLaunchKernelGGL(k_newx, dim3(GN), dim3(TPB), 0, stream, h2out, added, scale, nv2, newx2, CC);

  // ===== readout =====
  hipLaunchKernelGGL(k_graphpool, dim3(GN), dim3(TPB), 0, stream, newx2, nv2, batch, gsum, gcnt);
  hipLaunchKernelGGL(k_logsm, dim3(1), dim3(64), 0, stream, gsum, gcnt, out);
}